// Round 5
// baseline (389.553 us; speedup 1.0000x reference)
//
#include <hip/hip_runtime.h>
#include <cstdint>
#include <cstddef>

// ---------------- problem constants ----------------
#define D_MODEL   1024
#define D_STATE   16
#define D_CONV    4
#define D_INNER   2048
#define DT_RANK   64
#define NBATCH    2
#define SEQ       2048
#define NTOK      (NBATCH*SEQ)     // 4096 tokens
#define LN_EPSF   1e-5f
#define NCHUNK    64
#define TCHUNK    32               // SEQ / NCHUNK
#define KSPLIT    8                // x_proj split-K factor

typedef unsigned short u16;
typedef __bf16 bf16x8 __attribute__((ext_vector_type(8)));
typedef float  f32x4  __attribute__((ext_vector_type(4)));

__device__ __forceinline__ u16 f2bf(float f) {
  unsigned u = __float_as_uint(f);
  u += 0x7fffu + ((u >> 16) & 1u);          // round-to-nearest-even
  return (u16)(u >> 16);
}
__device__ __forceinline__ float bf2f(u16 v) {
  return __uint_as_float(((unsigned)v) << 16);
}
// unpack 8 bf16 (packed in uint4) -> 8 floats
__device__ __forceinline__ void unpack8(uint4 v, float* f) {
  f[0] = __uint_as_float(v.x << 16); f[1] = __uint_as_float(v.x & 0xffff0000u);
  f[2] = __uint_as_float(v.y << 16); f[3] = __uint_as_float(v.y & 0xffff0000u);
  f[4] = __uint_as_float(v.z << 16); f[5] = __uint_as_float(v.z & 0xffff0000u);
  f[6] = __uint_as_float(v.w << 16); f[7] = __uint_as_float(v.w & 0xffff0000u);
}

// async global->LDS, 16B per lane; lds dest must be wave-uniform base (+lane*16)
__device__ __forceinline__ void async16(const u16* g, u16* l) {
  __builtin_amdgcn_global_load_lds(
      (const __attribute__((address_space(1))) unsigned*)g,
      (__attribute__((address_space(3))) unsigned*)l, 16, 0, 0);
}

// ---------------- fused prep: all f32->bf16 conversions, 4 elems/thread ----------------
#define PN0 (NTOK*D_MODEL)          // x
#define PN1 (2*D_INNER*D_MODEL)     // W_in
#define PN2 (128*D_INNER)           // W_xproj (padded 96->128 rows)
#define PN3 (D_INNER*DT_RANK)       // W_dt
#define PN4 (D_MODEL*D_INNER)       // W_out
#define PTOT (PN0+PN1+PN2+PN3+PN4)
__global__ __launch_bounds__(256) void prep_k(
    const float* __restrict__ x, const float* __restrict__ W_in,
    const float* __restrict__ W_xproj, const float* __restrict__ W_dt,
    const float* __restrict__ W_out,
    u16* __restrict__ x_bf, u16* __restrict__ Win_bf, u16* __restrict__ Wxp_bf,
    u16* __restrict__ Wdt_bf, u16* __restrict__ Wout_bf)
{
  int i = (blockIdx.x * 256 + threadIdx.x) * 4;   // all segment sizes are 4-aligned
  const float* src; u16* dst; bool pad = false; int local = i;
  if (local < PN0)            { src = x;       dst = x_bf; }
  else if ((local -= PN0) < PN1) { src = W_in;    dst = Win_bf; }
  else if ((local -= PN1) < PN2) { src = W_xproj; dst = Wxp_bf; pad = (local >> 11) >= 96; }
  else if ((local -= PN2) < PN3) { src = W_dt;    dst = Wdt_bf; }
  else if ((local -= PN3) < PN4) { src = W_out;   dst = Wout_bf; }
  else return;
  ushort4 o;
  if (pad) { o = (ushort4){0,0,0,0}; }
  else {
    const float4 v = *(const float4*)(src + local);
    o = (ushort4){ f2bf(v.x), f2bf(v.y), f2bf(v.z), f2bf(v.w) };
  }
  *(ushort4*)(dst + local) = o;
}

// ---------------- bf16 NT GEMM: C[M,N] = A[M,K] * B[N,K]^T ----------------
// LDS tiles use an XOR swizzle on the 16B-chunk column (cc ^= row&3) to break
// the 4-way bank aliasing of 64B rows; applied at stage (source index) and read.
// EPI: 0=f32 store, 1=bf16 store, 2=softplus(acc+bias[col])->bf16, 3=acc+res f32,
//      4=f32 store into partial plane blockIdx.z (split-K; K range shifts by z)
template<int BM, int BN, int WTM, int WTN, int EPI>
__global__ __launch_bounds__(256) void gemm_nt(
    const u16* __restrict__ A, const u16* __restrict__ B,
    float* __restrict__ C, u16* __restrict__ Cb,
    const float* __restrict__ bias, const float* __restrict__ res,
    int kStart, int kEnd, int lda, int ldb, int ldc, size_t partStride)
{
  constexpr int BK = 32;
  constexpr int WAVES_N = BN / (16 * WTN);
  constexpr int ACH = BM * 4;             // 16B chunks in A tile (BK=32 bf16 = 4 chunks/row)
  constexpr int BCH = BN * 4;
  constexpr int ROUNDS = (ACH + BCH) / 256;

  __shared__ __align__(16) u16 lA[BM * BK];
  __shared__ __align__(16) u16 lB[BN * BK];

  const int tid  = threadIdx.x;
  const int w    = tid >> 6;
  const int lane = tid & 63;
  const int lrow = lane & 15;
  const int quad = lane >> 4;
  const int bm = blockIdx.y * BM;
  const int bn = blockIdx.x * BN;
  const int wave_m = (w / WAVES_N) * (16 * WTM);
  const int wave_n = (w % WAVES_N) * (16 * WTN);
  const int rquad = quad ^ (lrow & 3);    // swizzled read chunk

  int kOff = 0;
  if constexpr (EPI == 4) kOff = blockIdx.z * (kEnd - kStart);

  f32x4 acc[WTM][WTN];
  #pragma unroll
  for (int mi = 0; mi < WTM; ++mi)
    #pragma unroll
    for (int ni = 0; ni < WTN; ++ni)
      acc[mi][ni] = (f32x4){0.f, 0.f, 0.f, 0.f};

  for (int k0 = kStart + kOff; k0 < kEnd + kOff; k0 += BK) {
    #pragma unroll
    for (int r = 0; r < ROUNDS; ++r) {
      const int c0 = r * 256 + w * 64;    // wave-uniform chunk base
      const int c  = c0 + lane;
      if (c0 < ACH) {
        const int row = c >> 2, cc = (c & 3) ^ (row & 3);
        async16(A + (size_t)(bm + row) * lda + k0 + cc * 8, &lA[c0 * 8]);
      } else {
        const int cb = c - ACH, c0b = c0 - ACH;
        const int row = cb >> 2, cc = (cb & 3) ^ (row & 3);
        async16(B + (size_t)(bn + row) * ldb + k0 + cc * 8, &lB[c0b * 8]);
      }
    }
    __syncthreads();   // drain global_load_lds + join

    bf16x8 af[WTM], bfv[WTN];
    #pragma unroll
    for (int mi = 0; mi < WTM; ++mi)
      af[mi] = *(const bf16x8*)&lA[(wave_m + mi * 16 + lrow) * BK + rquad * 8];
    #pragma unroll
    for (int ni = 0; ni < WTN; ++ni)
      bfv[ni] = *(const bf16x8*)&lB[(wave_n + ni * 16 + lrow) * BK + rquad * 8];
    #pragma unroll
    for (int mi = 0; mi < WTM; ++mi)
      #pragma unroll
      for (int ni = 0; ni < WTN; ++ni)
        acc[mi][ni] = __builtin_amdgcn_mfma_f32_16x16x32_bf16(af[mi], bfv[ni], acc[mi][ni], 0, 0, 0);
    __syncthreads();   // all waves done reading before next overwrite
  }

  #pragma unroll
  for (int mi = 0; mi < WTM; ++mi) {
    #pragma unroll
    for (int ni = 0; ni < WTN; ++ni) {
      const int col  = bn + wave_n + ni * 16 + lrow;
      const int row0 = bm + wave_m + mi * 16 + quad * 4;
      #pragma unroll
      for (int r = 0; r < 4; ++r) {
        float v = acc[mi][ni][r];
        const size_t idx = (size_t)(row0 + r) * ldc + col;
        if constexpr (EPI == 0) {
          C[idx] = v;
        } else if constexpr (EPI == 1) {
          Cb[idx] = f2bf(v);
        } else if constexpr (EPI == 2) {
          v += bias[col];
          v = (v > 20.f) ? v : log1pf(__expf(v));   // softplus
          Cb[idx] = f2bf(v);
        } else if constexpr (EPI == 3) {
          C[idx] = v + res[idx];
        } else {
          C[(size_t)blockIdx.z * partStride + idx] = v;
        }
      }
    }
  }
}

// ---------------- split-K reduce + bf16 convert (x_proj) ----------------
__global__ __launch_bounds__(256) void reduce_conv_k(
    const float* __restrict__ part, u16* __restrict__ dst)
{
  const int i = blockIdx.x * 256 + threadIdx.x;     // over NTOK*128
  float s = 0.f;
  #pragma unroll
  for (int p = 0; p < KSPLIT; ++p)
    s += part[(size_t)p * (NTOK * 128) + i];
  dst[i] = f2bf(s);
}

// ---------------- causal depthwise conv (D_CONV=4) + SiLU -> bf16, 4 ch/thread ----------------
__global__ __launch_bounds__(256) void conv_silu_k(
    const u16* __restrict__ xz, const float* __restrict__ Wc,
    const float* __restrict__ bc, u16* __restrict__ ub)
{
  const int gid = (blockIdx.x * 256 + threadIdx.x) * 4;   // over NTOK*D_INNER
  const int e   = gid & (D_INNER - 1);
  const int tok = gid >> 11;
  const int l   = tok & (SEQ - 1);
  float acc[4];
  #pragma unroll
  for (int q = 0; q < 4; ++q) acc[q] = bc[e + q];
  #pragma unroll
  for (int j = 0; j < D_CONV; ++j) {
    const int li = l - 3 + j;
    if (li >= 0) {
      const ushort4 xv = *(const ushort4*)(xz + (size_t)(tok - 3 + j) * (2 * D_INNER) + e);
      acc[0] += bf2f(xv.x) * Wc[(e    ) * D_CONV + j];
      acc[1] += bf2f(xv.y) * Wc[(e + 1) * D_CONV + j];
      acc[2] += bf2f(xv.z) * Wc[(e + 2) * D_CONV + j];
      acc[3] += bf2f(xv.w) * Wc[(e + 3) * D_CONV + j];
    }
  }
  ushort4 o;
  {
    const float s0 = acc[0] / (1.f + __expf(-acc[0]));
    const float s1 = acc[1] / (1.f + __expf(-acc[1]));
    const float s2 = acc[2] / (1.f + __expf(-acc[2]));
    const float s3 = acc[3] / (1.f + __expf(-acc[3]));
    o = (ushort4){ f2bf(s0), f2bf(s1), f2bf(s2), f2bf(s3) };
  }
  *(ushort4*)(ub + gid) = o;
}

// ---------------- selective scan, chunk-parallel (3 passes) ----------------
// A_log = log(1..16) in this problem => A[n] = -(n+1) exactly; then
// exp(dlt*A[n]) = q^(n+1) with q = exp(-dlt): 1 exp + 15 muls instead of 16 exps.
// Validity is checked at runtime per-thread; slow path preserves generality.

// Pass 1: local scan with h=0 -> S[b,c,e,16], sum of delta -> sumd[b,c,e]
__global__ __launch_bounds__(256) void scan_p1(
    const u16* __restrict__ delta, const u16* __restrict__ ub,
    const u16* __restrict__ xdb, const float* __restrict__ A_log,
    float* __restrict__ S, float* __restrict__ sumd)
{
  const int e = blockIdx.x * 256 + threadIdx.x;
  const int c = blockIdx.y;
  const int b = blockIdx.z;
  float A[16], h[16];
  bool fast = true;
  #pragma unroll
  for (int n = 0; n < 16; ++n) {
    A[n] = -__expf(A_log[e * 16 + n]);
    fast = fast && (fabsf(A[n] + (float)(n + 1)) < 1e-3f);
    h[n] = 0.f;
  }
  float sd = 0.f;
  const int t0 = c * TCHUNK;
  #pragma unroll 2
  for (int t = 0; t < TCHUNK; ++t) {
    const size_t g = (size_t)(b * SEQ + t0 + t);
    const float dlt = bf2f(delta[g * D_INNER + e]);
    const float ut  = bf2f(ub[g * D_INNER + e]);
    float Bv[16];
    const u16* bp = xdb + g * 128 + DT_RANK;
    unpack8(*(const uint4*)bp, Bv);
    unpack8(*(const uint4*)(bp + 8), Bv + 8);
    sd += dlt;
    const float dbu = dlt * ut;
    float dA[16];
    if (fast) {
      const float q = __expf(-dlt);
      float p = 1.f;
      #pragma unroll
      for (int n = 0; n < 16; ++n) { p *= q; dA[n] = p; }
    } else {
      #pragma unroll
      for (int n = 0; n < 16; ++n) dA[n] = __expf(dlt * A[n]);
    }
    #pragma unroll
    for (int n = 0; n < 16; ++n)
      h[n] = dA[n] * h[n] + dbu * Bv[n];
  }
  const size_t idx = ((size_t)(b * NCHUNK + c) * D_INNER + e);
  #pragma unroll
  for (int q = 0; q < 4; ++q)
    *(f32x4*)&S[idx * 16 + q * 4] = (f32x4){h[q*4], h[q*4+1], h[q*4+2], h[q*4+3]};
  sumd[idx] = sd;
}

// Pass 2: sequential over chunks -> h_init[b,c,e,16]
__global__ __launch_bounds__(256) void scan_p2(
    const float* __restrict__ S, const float* __restrict__ sumd,
    const float* __restrict__ A_log, float* __restrict__ hinit)
{
  const int tid = blockIdx.x * 256 + threadIdx.x;   // 65536
  const int n = tid & 15;
  const int e = (tid >> 4) & (D_INNER - 1);
  const int b = tid >> 15;
  const float An = -__expf(A_log[e * 16 + n]);
  float h = 0.f;
  size_t idx = (size_t)b * NCHUNK * D_INNER + e;
  float s_cur  = S[idx * 16 + n];
  float sd_cur = sumd[idx];
  for (int c = 0; c < NCHUNK; ++c) {
    hinit[idx * 16 + n] = h;
    float s_nxt = 0.f, sd_nxt = 0.f;
    if (c + 1 < NCHUNK) {
      const size_t idx2 = idx + D_INNER;
      s_nxt  = S[idx2 * 16 + n];
      sd_nxt = sumd[idx2];
    }
    h = __expf(An * sd_cur) * h + s_cur;
    s_cur = s_nxt; sd_cur = sd_nxt;
    idx += D_INNER;
  }
}

// Pass 3: recompute chunk scan from h_init, fused y-dot + skip + gate -> yg (bf16)
__global__ __launch_bounds__(256) void scan_p3(
    const u16* __restrict__ delta, const u16* __restrict__ ub,
    const u16* __restrict__ xdb, const u16* __restrict__ xz,
    const float* __restrict__ A_log, const float* __restrict__ D_skip,
    const float* __restrict__ hinit, u16* __restrict__ yg)
{
  const int e = blockIdx.x * 256 + threadIdx.x;
  const int c = blockIdx.y;
  const int b = blockIdx.z;
  const size_t idx = ((size_t)(b * NCHUNK + c) * D_INNER + e);
  float A[16], h[16];
  bool fast = true;
  #pragma unroll
  for (int n = 0; n < 16; ++n) {
    A[n] = -__expf(A_log[e * 16 + n]);
    fast = fast && (fabsf(A[n] + (float)(n + 1)) < 1e-3f);
  }
  #pragma unroll
  for (int q = 0; q < 4; ++q) {
    f32x4 v = *(const f32x4*)&hinit[idx * 16 + q * 4];
    h[q*4] = v[0]; h[q*4+1] = v[1]; h[q*4+2] = v[2]; h[q*4+3] = v[3];
  }
  const float De = D_skip[e];
  const int t0 = c * TCHUNK;
  #pragma unroll 2
  for (int t = 0; t < TCHUNK; ++t) {
    const size_t g = (size_t)(b * SEQ + t0 + t);
    const float dlt = bf2f(delta[g * D_INNER + e]);
    const float ut  = bf2f(ub[g * D_INNER + e]);
    const float z   = bf2f(xz[g * (2 * D_INNER) + D_INNER + e]);
    float Bv[16], Cv[16];
    const u16* bp = xdb + g * 128 + DT_RANK;
    unpack8(*(const uint4*)bp, Bv);
    unpack8(*(const uint4*)(bp + 8), Bv + 8);
    unpack8(*(const uint4*)(bp + 16), Cv);
    unpack8(*(const uint4*)(bp + 24), Cv + 8);
    const float dbu = dlt * ut;
    float dA[16];
    if (fast) {
      const float q = __expf(-dlt);
      float p = 1.f;
      #pragma unroll
      for (int n = 0; n < 16; ++n) { p *= q; dA[n] = p; }
    } else {
      #pragma unroll
      for (int n = 0; n < 16; ++n) dA[n] = __expf(dlt * A[n]);
    }
    float y = 0.f;
    #pragma unroll
    for (int n = 0; n < 16; ++n) {
      h[n] = dA[n] * h[n] + dbu * Bv[n];
      y += h[n] * Cv[n];
    }
    y += ut * De;
    const float gt = z / (1.f + __expf(-z));
    yg[g * D_INNER + e] = f2bf(y * gt);
  }
}

// ---------------- LayerNorm, one block per token ----------------
__global__ __launch_bounds__(256) void ln_k(const float* __restrict__ pre,
                                            const float* __restrict__ gamma,
                                            const float* __restrict__ beta,
                                            float* __restrict__ out)
{
  const int tok = blockIdx.x;
  const int t   = threadIdx.x;
  const float* row = pre + (size_t)tok * D_MODEL;
  float v[4], s = 0.f, s2 = 0.f;
  #pragma unroll
  for (int i = 0; i < 4; ++i) {
    v[i] = row[t + i * 256];
    s += v[i]; s2 += v[i] * v[i];
  }
  #pragma unroll
  for (int off = 32; off >= 1; off >>= 1) {
    s  += __shfl_xor(s,  off);
    s2 += __shfl_xor(s2, off);
  }
  __shared__ float red[8];
  if ((t & 63) == 0) { red[t >> 6] = s; red[4 + (t >> 6)] = s2; }
  __syncthreads();
  if (t == 0) {
    const float ts  = red[0] + red[1] + red[2] + red[3];
    const float ts2 = red[4] + red[5] + red[6] + red[7];
    const float mu  = ts * (1.f / D_MODEL);
    const float var = ts2 * (1.f / D_MODEL) - mu * mu;
    red[0] = mu; red[1] = rsqrtf(var + LN_EPSF);
  }
  __syncthreads();
  const float mu = red[0], rv = red[1];
  #pragma unroll
  for (int i = 0; i < 4; ++i) {
    const int c = t + i * 256;
    out[(size_t)tok * D_MODEL + c] = (v[i] - mu) * rv * gamma[c] + beta[c];
  }
}

// ---------------- host launch ----------------
extern "C" void kernel_launch(void* const* d_in, const int* in_sizes, int n_in,
                              void* d_out, int out_size, void* d_ws, size_t ws_size,
                              hipStream_t stream) {
  const float* x       = (const float*)d_in[0];
  const float* W_in    = (const float*)d_in[1];
  const float* W_conv  = (const float*)d_in[2];
  const float* b_conv  = (const float*)d_in[3];
  const float* W_xproj = (const float*)d_in[4];
  const float* W_dt    = (const float*)d_in[5];
  const float* b_dt    = (const float*)d_in[6];
  const float* A_log   = (const float*)d_in[7];
  const float* D_skip  = (const float*)d_in[8];
  const float* W_out   = (const float*)d_in[9];
  const float* gamma   = (const float*)d_in[10];
  const float* beta    = (const float*)d_in[11];
  float* out = (float*)d_out;

  // workspace carve-up (256B aligned)
  char* ws = (char*)d_ws;
  size_t used = 0;
  auto alloc = [&](size_t bytes) -> char* {
    char* p = ws + used;
    used += (bytes + 255) & ~(size_t)255;
    return p;
  };
  u16* xz_bf     = (u16*)alloc((size_t)NTOK * 2 * D_INNER * 2);     // 33.5 MB
  float* pre     = (float*)alloc((size_t)NTOK * D_MODEL * 4);       // 16.8 MB; alias S
  char*  xw_reg  = alloc((size_t)NTOK * D_MODEL * 2 + (size_t)2 * D_INNER * D_MODEL * 2);
                                                                    // x_bf+Win_bf; alias hinit
  u16* u_bf      = (u16*)alloc((size_t)NTOK * D_INNER * 2);         // 16.8 MB
  u16* delta_bf  = (u16*)alloc((size_t)NTOK * D_INNER * 2);         // 16.8 MB
  u16* xdb_bf    = (u16*)alloc((size_t)NTOK * 128 * 2);             // 1 MB (96 padded to 128)
  u16* Wxp_bf    = (u16*)alloc((size_t)128 * D_INNER * 2);          // 0.5 MB
  u16* Wdt_bf    = (u16*)alloc((size_t)D_INNER * DT_RANK * 2);      // 0.26 MB
  u16* Wout_bf   = (u16*)alloc((size_t)D_MODEL * D_INNER * 2);      // 4.2 MB
  u16* yg_bf     = (u16*)alloc((size_t)NTOK * D_INNER * 2);         // 16.8 MB
  float* sumd    = (float*)alloc((size_t)NBATCH * NCHUNK * D_INNER * 4); // 1 MB
  float* xdb_part= (float*)alloc((size_t)KSPLIT * NTOK * 128 * 4);  // 16.8 MB

  // aliases (time-disjoint usage)
  u16* x_bf    = (u16*)xw_reg;                                    // dead after GEMM1
  u16* Win_bf  = (u16*)(xw_reg + (size_t)NTOK * D_MODEL * 2);     // dead after GEMM1
  float* S     = pre;                                             // pre written at stage 6
  float* hinit = (float*)xw_reg;                                  // 16.8 MB, after GEMM1

  if (ws_size < used) {   // signal: NaN output (insufficient workspace)
    hipMemsetAsync(d_out, 0xFF, (size_t)out_size * 4, stream);
    return;
  }

  const dim3 blk(256);

  // 0) all f32->bf16 conversions in one kernel (4 elems/thread)
  prep_k<<<(PTOT / 4 + 255) / 256, blk, 0, stream>>>(
      x, W_in, W_xproj, W_dt, W_out, x_bf, Win_bf, Wxp_bf, Wdt_bf, Wout_bf);

  // 1) in_proj: xz[4096,4096] = x[4096,1024] * W_in[4096,1024]^T  (bf16 out)
  gemm_nt<128,128,4,4,1><<<dim3((2*D_INNER)/128, NTOK/128), blk, 0, stream>>>(
      x_bf, Win_bf, nullptr, xz_bf, nullptr, nullptr,
      0, D_MODEL, D_MODEL, D_MODEL, 2*D_INNER, 0);

  // 2) causal depthwise conv + silu -> u (bf16)
  conv_silu_k<<<(NTOK * D_INNER) / 1024, blk, 0, stream>>>(xz_bf, W_conv, b_conv, u_bf);

  // 3) x_proj split-K=8: partials[8][4096][128] = u * W_xproj^T
  gemm_nt<64,128,1,8,4><<<dim3(1, NTOK/64, KSPLIT), blk, 0, stream>>>(
      u_bf, Wxp_bf, xdb_part, nullptr, nullptr, nullptr,
      0, D_INNER / KSPLIT, D_INNER, D_INNER, 128, (size_t)NTOK * 128);
  reduce_conv_k<<<(NTOK * 128) / 256, blk, 0, stream>>>(xdb_part, xdb_bf);

  // 4) dt_proj + bias + softplus: delta[4096,2048] -> bf16
  gemm_nt<128,128,4,4,2><<<dim3(D_INNER/128, NTOK/128), blk, 0, stream>>>(
      xdb_bf, Wdt_bf, nullptr, delta_bf, b_dt, nullptr,
      0, DT_RANK, 128, DT_RANK, D_INNER, 0);

  // 5) chunk-parallel selective scan + skip + gate -> yg (bf16)
  scan_p1<<<dim3(D_INNER/256, NCHUNK, NBATCH), blk, 0, stream>>>(
      delta_bf, u_bf, xdb_bf, A_log, S, sumd);
  scan_p2<<<(NBATCH * D_INNER * D_STATE) / 256, blk, 0, stream>>>(
      S, sumd, A_log, hinit);
  scan_p3<<<dim3(D_INNER/256, NCHUNK, NBATCH), blk, 0, stream>>>(
      delta_bf, u_bf, xdb_bf, xz_bf, A_log, D_skip, hinit, yg_bf);

  // 6) out_proj + residual: pre[4096,1024] = yg * W_out^T + x   (128x64 tiles, 512 blocks)
  gemm_nt<128,64,4,2,3><<<dim3(D_MODEL/64, NTOK/128), blk, 0, stream>>>(
      yg_bf, Wout_bf, pre, nullptr, nullptr, x,
      0, D_INNER, D_INNER, D_INNER, D_MODEL, 0);

  // 7) LayerNorm
  ln_k<<<NTOK, blk, 0, stream>>>(pre, gamma, beta, out);
}

// Round 6
// 336.387 us; speedup vs baseline: 1.1581x; 1.1581x over previous
//
#include <hip/hip_runtime.h>
#include <cstdint>
#include <cstddef>

// ---------------- problem constants ----------------
#define D_MODEL   1024
#define D_STATE   16
#define D_CONV    4
#define D_INNER   2048
#define DT_RANK   64
#define NBATCH    2
#define SEQ       2048
#define NTOK      (NBATCH*SEQ)     // 4096 tokens
#define LN_EPSF   1e-5f
#define NCHUNK    64
#define TCHUNK    32               // SEQ / NCHUNK
#define KSPLIT    8                // x_proj split-K factor

typedef unsigned short u16;
typedef __bf16 bf16x8 __attribute__((ext_vector_type(8)));
typedef float  f32x4  __attribute__((ext_vector_type(4)));

__device__ __forceinline__ u16 f2bf(float f) {
  unsigned u = __float_as_uint(f);
  u += 0x7fffu + ((u >> 16) & 1u);          // round-to-nearest-even
  return (u16)(u >> 16);
}
__device__ __forceinline__ float bf2f(u16 v) {
  return __uint_as_float(((unsigned)v) << 16);
}
// unpack 8 bf16 (packed in uint4) -> 8 floats
__device__ __forceinline__ void unpack8(uint4 v, float* f) {
  f[0] = __uint_as_float(v.x << 16); f[1] = __uint_as_float(v.x & 0xffff0000u);
  f[2] = __uint_as_float(v.y << 16); f[3] = __uint_as_float(v.y & 0xffff0000u);
  f[4] = __uint_as_float(v.z << 16); f[5] = __uint_as_float(v.z & 0xffff0000u);
  f[6] = __uint_as_float(v.w << 16); f[7] = __uint_as_float(v.w & 0xffff0000u);
}

// async global->LDS, 16B per lane; lds dest must be wave-uniform base (+lane*16)
__device__ __forceinline__ void async16(const u16* g, u16* l) {
  __builtin_amdgcn_global_load_lds(
      (const __attribute__((address_space(1))) unsigned*)g,
      (__attribute__((address_space(3))) unsigned*)l, 16, 0, 0);
}

// ---------------- fused prep: all f32->bf16 conversions, 4 elems/thread ----------------
#define PN0 (NTOK*D_MODEL)          // x
#define PN1 (2*D_INNER*D_MODEL)     // W_in
#define PN2 (128*D_INNER)           // W_xproj (padded 96->128 rows)
#define PN3 (D_INNER*DT_RANK)       // W_dt
#define PN4 (D_MODEL*D_INNER)       // W_out
#define PTOT (PN0+PN1+PN2+PN3+PN4)
__global__ __launch_bounds__(256) void prep_k(
    const float* __restrict__ x, const float* __restrict__ W_in,
    const float* __restrict__ W_xproj, const float* __restrict__ W_dt,
    const float* __restrict__ W_out,
    u16* __restrict__ x_bf, u16* __restrict__ Win_bf, u16* __restrict__ Wxp_bf,
    u16* __restrict__ Wdt_bf, u16* __restrict__ Wout_bf)
{
  int i = (blockIdx.x * 256 + threadIdx.x) * 4;   // all segment sizes are 4-aligned
  const float* src; u16* dst; bool pad = false; int local = i;
  if (local < PN0)            { src = x;       dst = x_bf; }
  else if ((local -= PN0) < PN1) { src = W_in;    dst = Win_bf; }
  else if ((local -= PN1) < PN2) { src = W_xproj; dst = Wxp_bf; pad = (local >> 11) >= 96; }
  else if ((local -= PN2) < PN3) { src = W_dt;    dst = Wdt_bf; }
  else if ((local -= PN3) < PN4) { src = W_out;   dst = Wout_bf; }
  else return;
  ushort4 o;
  if (pad) { o = (ushort4){0,0,0,0}; }
  else {
    const float4 v = *(const float4*)(src + local);
    o = (ushort4){ f2bf(v.x), f2bf(v.y), f2bf(v.z), f2bf(v.w) };
  }
  *(ushort4*)(dst + local) = o;
}

// ---------------- bf16 NT GEMM: C[M,N] = A[M,K] * B[N,K]^T ----------------
// LDS tiles use an XOR swizzle on the 16B-chunk column (cc ^= row&3) to break
// the 4-way bank aliasing of 64B rows; applied at stage (source index) and read.
// EPI: 0=f32 store, 1=bf16 store, 2=softplus(acc+bias[col])->bf16, 3=acc+res f32,
//      4=f32 store into partial plane blockIdx.z (split-K; K range shifts by z)
template<int BM, int BN, int WTM, int WTN, int EPI>
__global__ __launch_bounds__(256) void gemm_nt(
    const u16* __restrict__ A, const u16* __restrict__ B,
    float* __restrict__ C, u16* __restrict__ Cb,
    const float* __restrict__ bias, const float* __restrict__ res,
    int kStart, int kEnd, int lda, int ldb, int ldc, size_t partStride)
{
  constexpr int BK = 32;
  constexpr int WAVES_N = BN / (16 * WTN);
  constexpr int ACH = BM * 4;             // 16B chunks in A tile (BK=32 bf16 = 4 chunks/row)
  constexpr int BCH = BN * 4;
  constexpr int ROUNDS = (ACH + BCH) / 256;

  __shared__ __align__(16) u16 lA[BM * BK];
  __shared__ __align__(16) u16 lB[BN * BK];

  const int tid  = threadIdx.x;
  const int w    = tid >> 6;
  const int lane = tid & 63;
  const int lrow = lane & 15;
  const int quad = lane >> 4;
  const int bm = blockIdx.y * BM;
  const int bn = blockIdx.x * BN;
  const int wave_m = (w / WAVES_N) * (16 * WTM);
  const int wave_n = (w % WAVES_N) * (16 * WTN);
  const int rquad = quad ^ (lrow & 3);    // swizzled read chunk

  int kOff = 0;
  if constexpr (EPI == 4) kOff = blockIdx.z * (kEnd - kStart);

  f32x4 acc[WTM][WTN];
  #pragma unroll
  for (int mi = 0; mi < WTM; ++mi)
    #pragma unroll
    for (int ni = 0; ni < WTN; ++ni)
      acc[mi][ni] = (f32x4){0.f, 0.f, 0.f, 0.f};

  for (int k0 = kStart + kOff; k0 < kEnd + kOff; k0 += BK) {
    #pragma unroll
    for (int r = 0; r < ROUNDS; ++r) {
      const int c0 = r * 256 + w * 64;    // wave-uniform chunk base
      const int c  = c0 + lane;
      if (c0 < ACH) {
        const int row = c >> 2, cc = (c & 3) ^ (row & 3);
        async16(A + (size_t)(bm + row) * lda + k0 + cc * 8, &lA[c0 * 8]);
      } else {
        const int cb = c - ACH, c0b = c0 - ACH;
        const int row = cb >> 2, cc = (cb & 3) ^ (row & 3);
        async16(B + (size_t)(bn + row) * ldb + k0 + cc * 8, &lB[c0b * 8]);
      }
    }
    __syncthreads();   // drain global_load_lds + join

    bf16x8 af[WTM], bfv[WTN];
    #pragma unroll
    for (int mi = 0; mi < WTM; ++mi)
      af[mi] = *(const bf16x8*)&lA[(wave_m + mi * 16 + lrow) * BK + rquad * 8];
    #pragma unroll
    for (int ni = 0; ni < WTN; ++ni)
      bfv[ni] = *(const bf16x8*)&lB[(wave_n + ni * 16 + lrow) * BK + rquad * 8];
    #pragma unroll
    for (int mi = 0; mi < WTM; ++mi)
      #pragma unroll
      for (int ni = 0; ni < WTN; ++ni)
        acc[mi][ni] = __builtin_amdgcn_mfma_f32_16x16x32_bf16(af[mi], bfv[ni], acc[mi][ni], 0, 0, 0);
    __syncthreads();   // all waves done reading before next overwrite
  }

  #pragma unroll
  for (int mi = 0; mi < WTM; ++mi) {
    #pragma unroll
    for (int ni = 0; ni < WTN; ++ni) {
      const int col  = bn + wave_n + ni * 16 + lrow;
      const int row0 = bm + wave_m + mi * 16 + quad * 4;
      #pragma unroll
      for (int r = 0; r < 4; ++r) {
        float v = acc[mi][ni][r];
        const size_t idx = (size_t)(row0 + r) * ldc + col;
        if constexpr (EPI == 0) {
          C[idx] = v;
        } else if constexpr (EPI == 1) {
          Cb[idx] = f2bf(v);
        } else if constexpr (EPI == 2) {
          v += bias[col];
          v = (v > 20.f) ? v : log1pf(__expf(v));   // softplus
          Cb[idx] = f2bf(v);
        } else if constexpr (EPI == 3) {
          C[idx] = v + res[idx];
        } else {
          C[(size_t)blockIdx.z * partStride + idx] = v;
        }
      }
    }
  }
}

// ---------------- split-K reduce + bf16 convert (x_proj) ----------------
__global__ __launch_bounds__(256) void reduce_conv_k(
    const float* __restrict__ part, u16* __restrict__ dst)
{
  const int i = blockIdx.x * 256 + threadIdx.x;     // over NTOK*128
  float s = 0.f;
  #pragma unroll
  for (int p = 0; p < KSPLIT; ++p)
    s += part[(size_t)p * (NTOK * 128) + i];
  dst[i] = f2bf(s);
}

// ---------------- causal depthwise conv (D_CONV=4) + SiLU -> bf16 ----------------
// Sliding window: each thread handles 8 consecutive tokens x 4 channels.
// Weight loads are contiguous float4 (coalescing restored); xz rows loaded once
// into a register window (11 row-loads per 8 tokens instead of 32).
#define CONV_T 8
__global__ __launch_bounds__(256) void conv_silu_k(
    const u16* __restrict__ xz, const float* __restrict__ Wc,
    const float* __restrict__ bc, u16* __restrict__ ub)
{
  const int tid = blockIdx.x * 256 + threadIdx.x;   // 512 groups * 512 tokblocks
  const int e   = (tid & 511) * 4;                  // channel group (consecutive lanes -> coalesced)
  const int tb  = tid >> 9;
  const int tok0 = tb * CONV_T;
  const int l0   = tok0 & (SEQ - 1);

  // weights: Wc[(e+q)*4 + j] -> four contiguous float4 per thread
  float4 wq[4];
  #pragma unroll
  for (int q = 0; q < 4; ++q) wq[q] = *(const float4*)(Wc + (e + q) * 4);
  const float4 bcv = *(const float4*)(bc + e);

  // window: p3 = x[t-3], p2 = x[t-2], p1 = x[t-1] (channels e..e+3)
  float p3[4], p2[4], p1[4];
  if (l0 == 0) {
    #pragma unroll
    for (int q = 0; q < 4; ++q) { p3[q] = 0.f; p2[q] = 0.f; p1[q] = 0.f; }
  } else {
    const ushort4 a = *(const ushort4*)(xz + (size_t)(tok0 - 3) * (2 * D_INNER) + e);
    const ushort4 b = *(const ushort4*)(xz + (size_t)(tok0 - 2) * (2 * D_INNER) + e);
    const ushort4 c = *(const ushort4*)(xz + (size_t)(tok0 - 1) * (2 * D_INNER) + e);
    p3[0]=bf2f(a.x); p3[1]=bf2f(a.y); p3[2]=bf2f(a.z); p3[3]=bf2f(a.w);
    p2[0]=bf2f(b.x); p2[1]=bf2f(b.y); p2[2]=bf2f(b.z); p2[3]=bf2f(b.w);
    p1[0]=bf2f(c.x); p1[1]=bf2f(c.y); p1[2]=bf2f(c.z); p1[3]=bf2f(c.w);
  }

  #pragma unroll
  for (int tt = 0; tt < CONV_T; ++tt) {
    const ushort4 xv = *(const ushort4*)(xz + (size_t)(tok0 + tt) * (2 * D_INNER) + e);
    float cur[4] = { bf2f(xv.x), bf2f(xv.y), bf2f(xv.z), bf2f(xv.w) };
    ushort4 o;
    u16* op = (u16*)&o;
    #pragma unroll
    for (int q = 0; q < 4; ++q) {
      const float acc = bcv.x * 0.f + bc[0] * 0.f +   // (placeholder removed below)
                        0.f;
      (void)acc;
    }
    {
      float a0 = ((const float*)&bcv)[0] + p3[0]*wq[0].x + p2[0]*wq[0].y + p1[0]*wq[0].z + cur[0]*wq[0].w;
      float a1 = ((const float*)&bcv)[1] + p3[1]*wq[1].x + p2[1]*wq[1].y + p1[1]*wq[1].z + cur[1]*wq[1].w;
      float a2 = ((const float*)&bcv)[2] + p3[2]*wq[2].x + p2[2]*wq[2].y + p1[2]*wq[2].z + cur[2]*wq[2].w;
      float a3 = ((const float*)&bcv)[3] + p3[3]*wq[3].x + p2[3]*wq[3].y + p1[3]*wq[3].z + cur[3]*wq[3].w;
      op[0] = f2bf(a0 / (1.f + __expf(-a0)));
      op[1] = f2bf(a1 / (1.f + __expf(-a1)));
      op[2] = f2bf(a2 / (1.f + __expf(-a2)));
      op[3] = f2bf(a3 / (1.f + __expf(-a3)));
    }
    *(ushort4*)(ub + (size_t)(tok0 + tt) * D_INNER + e) = o;
    #pragma unroll
    for (int q = 0; q < 4; ++q) { p3[q] = p2[q]; p2[q] = p1[q]; p1[q] = cur[q]; }
  }
}

// ---------------- selective scan, chunk-parallel (3 passes) ----------------
// A_log = log(1..16) in this problem => A[n] = -(n+1) exactly; then
// exp(dlt*A[n]) = q^(n+1) with q = exp(-dlt): 1 exp + 15 muls instead of 16 exps.
// Validity is checked at runtime per-thread; slow path preserves generality.

// Pass 1: local scan with h=0 -> S[b,c,e,16], sum of delta -> sumd[b,c,e]
__global__ __launch_bounds__(256) void scan_p1(
    const u16* __restrict__ delta, const u16* __restrict__ ub,
    const u16* __restrict__ xdb, const float* __restrict__ A_log,
    float* __restrict__ S, float* __restrict__ sumd)
{
  const int e = blockIdx.x * 256 + threadIdx.x;
  const int c = blockIdx.y;
  const int b = blockIdx.z;
  float A[16], h[16];
  bool fast = true;
  #pragma unroll
  for (int n = 0; n < 16; ++n) {
    A[n] = -__expf(A_log[e * 16 + n]);
    fast = fast && (fabsf(A[n] + (float)(n + 1)) < 1e-3f);
    h[n] = 0.f;
  }
  float sd = 0.f;
  const int t0 = c * TCHUNK;
  #pragma unroll 2
  for (int t = 0; t < TCHUNK; ++t) {
    const size_t g = (size_t)(b * SEQ + t0 + t);
    const float dlt = bf2f(delta[g * D_INNER + e]);
    const float ut  = bf2f(ub[g * D_INNER + e]);
    float Bv[16];
    const u16* bp = xdb + g * 128 + DT_RANK;
    unpack8(*(const uint4*)bp, Bv);
    unpack8(*(const uint4*)(bp + 8), Bv + 8);
    sd += dlt;
    const float dbu = dlt * ut;
    float dA[16];
    if (fast) {
      const float q = __expf(-dlt);
      float p = 1.f;
      #pragma unroll
      for (int n = 0; n < 16; ++n) { p *= q; dA[n] = p; }
    } else {
      #pragma unroll
      for (int n = 0; n < 16; ++n) dA[n] = __expf(dlt * A[n]);
    }
    #pragma unroll
    for (int n = 0; n < 16; ++n)
      h[n] = dA[n] * h[n] + dbu * Bv[n];
  }
  const size_t idx = ((size_t)(b * NCHUNK + c) * D_INNER + e);
  #pragma unroll
  for (int q = 0; q < 4; ++q)
    *(f32x4*)&S[idx * 16 + q * 4] = (f32x4){h[q*4], h[q*4+1], h[q*4+2], h[q*4+3]};
  sumd[idx] = sd;
}

// Pass 2: sequential over chunks -> h_init[b,c,e,16]
__global__ __launch_bounds__(256) void scan_p2(
    const float* __restrict__ S, const float* __restrict__ sumd,
    const float* __restrict__ A_log, float* __restrict__ hinit)
{
  const int tid = blockIdx.x * 256 + threadIdx.x;   // 65536
  const int n = tid & 15;
  const int e = (tid >> 4) & (D_INNER - 1);
  const int b = tid >> 15;
  const float An = -__expf(A_log[e * 16 + n]);
  float h = 0.f;
  size_t idx = (size_t)b * NCHUNK * D_INNER + e;
  float s_cur  = S[idx * 16 + n];
  float sd_cur = sumd[idx];
  for (int c = 0; c < NCHUNK; ++c) {
    hinit[idx * 16 + n] = h;
    float s_nxt = 0.f, sd_nxt = 0.f;
    if (c + 1 < NCHUNK) {
      const size_t idx2 = idx + D_INNER;
      s_nxt  = S[idx2 * 16 + n];
      sd_nxt = sumd[idx2];
    }
    h = __expf(An * sd_cur) * h + s_cur;
    s_cur = s_nxt; sd_cur = sd_nxt;
    idx += D_INNER;
  }
}

// Pass 3: recompute chunk scan from h_init, fused y-dot + skip + gate -> yg (bf16)
__global__ __launch_bounds__(256) void scan_p3(
    const u16* __restrict__ delta, const u16* __restrict__ ub,
    const u16* __restrict__ xdb, const u16* __restrict__ xz,
    const float* __restrict__ A_log, const float* __restrict__ D_skip,
    const float* __restrict__ hinit, u16* __restrict__ yg)
{
  const int e = blockIdx.x * 256 + threadIdx.x;
  const int c = blockIdx.y;
  const int b = blockIdx.z;
  const size_t idx = ((size_t)(b * NCHUNK + c) * D_INNER + e);
  float A[16], h[16];
  bool fast = true;
  #pragma unroll
  for (int n = 0; n < 16; ++n) {
    A[n] = -__expf(A_log[e * 16 + n]);
    fast = fast && (fabsf(A[n] + (float)(n + 1)) < 1e-3f);
  }
  #pragma unroll
  for (int q = 0; q < 4; ++q) {
    f32x4 v = *(const f32x4*)&hinit[idx * 16 + q * 4];
    h[q*4] = v[0]; h[q*4+1] = v[1]; h[q*4+2] = v[2]; h[q*4+3] = v[3];
  }
  const float De = D_skip[e];
  const int t0 = c * TCHUNK;
  #pragma unroll 2
  for (int t = 0; t < TCHUNK; ++t) {
    const size_t g = (size_t)(b * SEQ + t0 + t);
    const float dlt = bf2f(delta[g * D_INNER + e]);
    const float ut  = bf2f(ub[g * D_INNER + e]);
    const float z   = bf2f(xz[g * (2 * D_INNER) + D_INNER + e]);
    float Bv[16], Cv[16];
    const u16* bp = xdb + g * 128 + DT_RANK;
    unpack8(*(const uint4*)bp, Bv);
    unpack8(*(const uint4*)(bp + 8), Bv + 8);
    unpack8(*(const uint4*)(bp + 16), Cv);
    unpack8(*(const uint4*)(bp + 24), Cv + 8);
    const float dbu = dlt * ut;
    float dA[16];
    if (fast) {
      const float q = __expf(-dlt);
      float p = 1.f;
      #pragma unroll
      for (int n = 0; n < 16; ++n) { p *= q; dA[n] = p; }
    } else {
      #pragma unroll
      for (int n = 0; n < 16; ++n) dA[n] = __expf(dlt * A[n]);
    }
    float y = 0.f;
    #pragma unroll
    for (int n = 0; n < 16; ++n) {
      h[n] = dA[n] * h[n] + dbu * Bv[n];
      y += h[n] * Cv[n];
    }
    y += ut * De;
    const float gt = z / (1.f + __expf(-z));
    yg[g * D_INNER + e] = f2bf(y * gt);
  }
}

// ---------------- LayerNorm, one block per token ----------------
__global__ __launch_bounds__(256) void ln_k(const float* __restrict__ pre,
                                            const float* __restrict__ gamma,
                                            const float* __restrict__ beta,
                                            float* __restrict__ out)
{
  const int tok = blockIdx.x;
  const int t   = threadIdx.x;
  const float* row = pre + (size_t)tok * D_MODEL;
  float v[4], s = 0.f, s2 = 0.f;
  #pragma unroll
  for (int i = 0; i < 4; ++i) {
    v[i] = row[t + i * 256];
    s += v[i]; s2 += v[i] * v[i];
  }
  #pragma unroll
  for (int off = 32; off >= 1; off >>= 1) {
    s  += __shfl_xor(s,  off);
    s2 += __shfl_xor(s2, off);
  }
  __shared__ float red[8];
  if ((t & 63) == 0) { red[t >> 6] = s; red[4 + (t >> 6)] = s2; }
  __syncthreads();
  if (t == 0) {
    const float ts  = red[0] + red[1] + red[2] + red[3];
    const float ts2 = red[4] + red[5] + red[6] + red[7];
    const float mu  = ts * (1.f / D_MODEL);
    const float var = ts2 * (1.f / D_MODEL) - mu * mu;
    red[0] = mu; red[1] = rsqrtf(var + LN_EPSF);
  }
  __syncthreads();
  const float mu = red[0], rv = red[1];
  #pragma unroll
  for (int i = 0; i < 4; ++i) {
    const int c = t + i * 256;
    out[(size_t)tok * D_MODEL + c] = (v[i] - mu) * rv * gamma[c] + beta[c];
  }
}

// ---------------- host launch ----------------
extern "C" void kernel_launch(void* const* d_in, const int* in_sizes, int n_in,
                              void* d_out, int out_size, void* d_ws, size_t ws_size,
                              hipStream_t stream) {
  const float* x       = (const float*)d_in[0];
  const float* W_in    = (const float*)d_in[1];
  const float* W_conv  = (const float*)d_in[2];
  const float* b_conv  = (const float*)d_in[3];
  const float* W_xproj = (const float*)d_in[4];
  const float* W_dt    = (const float*)d_in[5];
  const float* b_dt    = (const float*)d_in[6];
  const float* A_log   = (const float*)d_in[7];
  const float* D_skip  = (const float*)d_in[8];
  const float* W_out   = (const float*)d_in[9];
  const float* gamma   = (const float*)d_in[10];
  const float* beta    = (const float*)d_in[11];
  float* out = (float*)d_out;

  // workspace carve-up (256B aligned)
  char* ws = (char*)d_ws;
  size_t used = 0;
  auto alloc = [&](size_t bytes) -> char* {
    char* p = ws + used;
    used += (bytes + 255) & ~(size_t)255;
    return p;
  };
  u16* xz_bf     = (u16*)alloc((size_t)NTOK * 2 * D_INNER * 2);     // 33.5 MB
  float* pre     = (float*)alloc((size_t)NTOK * D_MODEL * 4);       // 16.8 MB; alias S
  char*  xw_reg  = alloc((size_t)NTOK * D_MODEL * 2 + (size_t)2 * D_INNER * D_MODEL * 2);
                                                                    // x_bf+Win_bf; alias hinit
  u16* u_bf      = (u16*)alloc((size_t)NTOK * D_INNER * 2);         // 16.8 MB
  u16* delta_bf  = (u16*)alloc((size_t)NTOK * D_INNER * 2);         // 16.8 MB
  u16* xdb_bf    = (u16*)alloc((size_t)NTOK * 128 * 2);             // 1 MB (96 padded to 128)
  u16* Wxp_bf    = (u16*)alloc((size_t)128 * D_INNER * 2);          // 0.5 MB
  u16* Wdt_bf    = (u16*)alloc((size_t)D_INNER * DT_RANK * 2);      // 0.26 MB
  u16* Wout_bf   = (u16*)alloc((size_t)D_MODEL * D_INNER * 2);      // 4.2 MB
  u16* yg_bf     = (u16*)alloc((size_t)NTOK * D_INNER * 2);         // 16.8 MB
  float* sumd    = (float*)alloc((size_t)NBATCH * NCHUNK * D_INNER * 4); // 1 MB
  float* xdb_part= (float*)alloc((size_t)KSPLIT * NTOK * 128 * 4);  // 16.8 MB

  // aliases (time-disjoint usage)
  u16* x_bf    = (u16*)xw_reg;                                    // dead after GEMM1
  u16* Win_bf  = (u16*)(xw_reg + (size_t)NTOK * D_MODEL * 2);     // dead after GEMM1
  float* S     = pre;                                             // pre written at stage 6
  float* hinit = (float*)xw_reg;                                  // 16.8 MB, after GEMM1

  if (ws_size < used) {   // signal: NaN output (insufficient workspace)
    hipMemsetAsync(d_out, 0xFF, (size_t)out_size * 4, stream);
    return;
  }

  const dim3 blk(256);

  // 0) all f32->bf16 conversions in one kernel (4 elems/thread)
  prep_k<<<(PTOT / 4 + 255) / 256, blk, 0, stream>>>(
      x, W_in, W_xproj, W_dt, W_out, x_bf, Win_bf, Wxp_bf, Wdt_bf, Wout_bf);

  // 1) in_proj: xz[4096,4096] = x[4096,1024] * W_in[4096,1024]^T  (bf16 out)
  gemm_nt<128,128,4,4,1><<<dim3((2*D_INNER)/128, NTOK/128), blk, 0, stream>>>(
      x_bf, Win_bf, nullptr, xz_bf, nullptr, nullptr,
      0, D_MODEL, D_MODEL, D_MODEL, 2*D_INNER, 0);

  // 2) causal depthwise conv + silu -> u (bf16): 8 tokens x 4 channels per thread
  conv_silu_k<<<(NTOK / CONV_T) * (D_INNER / 4) / 256, blk, 0, stream>>>(
      xz_bf, W_conv, b_conv, u_bf);

  // 3) x_proj split-K=8: partials[8][4096][128] = u * W_xproj^T
  gemm_nt<64,128,1,8,4><<<dim3(1, NTOK/64, KSPLIT), blk, 0, stream>>>(
      u_bf, Wxp_bf, xdb_part, nullptr, nullptr, nullptr,
      0, D_INNER / KSPLIT, D_INNER, D_INNER, 128, (size_t)NTOK * 128);
  reduce_conv_k<<<(NTOK * 128) / 256, blk, 0, stream>>>(xdb_part, xdb_bf);

  // 4) dt_proj + bias + softplus: delta[4096,2048] -> bf16
  gemm_nt<128,128,4,4,2><<<dim3(D_INNER/128, NTOK/128), blk, 0, stream>>>(
      xdb_bf, Wdt_bf, nullptr, delta_bf, b_dt, nullptr,
      0, DT_RANK, 128, DT_RANK, D_INNER, 0);

  // 5) chunk-parallel selective scan + skip + gate -> yg (bf16)
  scan_p1<<<dim3(D_INNER/256, NCHUNK, NBATCH), blk, 0, stream>>>(
      delta_bf, u_bf, xdb_bf, A_log, S, sumd);
  scan_p2<<<(NBATCH * D_INNER * D_STATE) / 256, blk, 0, stream>>>(
      S, sumd, A_log, hinit);
  scan_p3<<<dim3(D_INNER/256, NCHUNK, NBATCH), blk, 0, stream>>>(
      delta_bf, u_bf, xdb_bf, xz_bf, A_log, D_skip, hinit, yg_bf);

  // 6) out_proj + residual: pre[4096,1024] = yg * W_out^T + x   (128x64 tiles, 512 blocks)
  gemm_nt<128,64,4,2,3><<<dim3(D_MODEL/64, NTOK/128), blk, 0, stream>>>(
      yg_bf, Wout_bf, pre, nullptr, nullptr, x,
      0, D_INNER, D_INNER, D_INNER, D_MODEL, 0);

  // 7) LayerNorm
  ln_k<<<NTOK, blk, 0, stream>>>(pre, gamma, beta, out);
}

// Round 7
// 312.107 us; speedup vs baseline: 1.2481x; 1.0778x over previous
//
#include <hip/hip_runtime.h>
#include <cstdint>
#include <cstddef>

// ---------------- problem constants ----------------
#define D_MODEL   1024
#define D_STATE   16
#define D_CONV    4
#define D_INNER   2048
#define DT_RANK   64
#define NBATCH    2
#define SEQ       2048
#define NTOK      (NBATCH*SEQ)     // 4096 tokens
#define LN_EPSF   1e-5f
#define NCHUNK    64
#define TCHUNK    32               // SEQ / NCHUNK
#define KSPLIT    8                // x_proj split-K factor

typedef unsigned short u16;
typedef __bf16 bf16x8 __attribute__((ext_vector_type(8)));
typedef float  f32x4  __attribute__((ext_vector_type(4)));

__device__ __forceinline__ u16 f2bf(float f) {
  unsigned u = __float_as_uint(f);
  u += 0x7fffu + ((u >> 16) & 1u);          // round-to-nearest-even
  return (u16)(u >> 16);
}
__device__ __forceinline__ float bf2f(u16 v) {
  return __uint_as_float(((unsigned)v) << 16);
}
// unpack 8 bf16 (packed in uint4) -> 8 floats
__device__ __forceinline__ void unpack8(uint4 v, float* f) {
  f[0] = __uint_as_float(v.x << 16); f[1] = __uint_as_float(v.x & 0xffff0000u);
  f[2] = __uint_as_float(v.y << 16); f[3] = __uint_as_float(v.y & 0xffff0000u);
  f[4] = __uint_as_float(v.z << 16); f[5] = __uint_as_float(v.z & 0xffff0000u);
  f[6] = __uint_as_float(v.w << 16); f[7] = __uint_as_float(v.w & 0xffff0000u);
}

// async global->LDS, 16B per lane; lds dest must be wave-uniform base (+lane*16)
__device__ __forceinline__ void async16(const u16* g, u16* l) {
  __builtin_amdgcn_global_load_lds(
      (const __attribute__((address_space(1))) unsigned*)g,
      (__attribute__((address_space(3))) unsigned*)l, 16, 0, 0);
}

// ---------------- fused prep: all f32->bf16 conversions, 4 elems/thread ----------------
#define PN0 (NTOK*D_MODEL)          // x
#define PN1 (2*D_INNER*D_MODEL)     // W_in
#define PN2 (128*D_INNER)           // W_xproj (padded 96->128 rows)
#define PN3 (D_INNER*DT_RANK)       // W_dt
#define PN4 (D_MODEL*D_INNER)       // W_out
#define PTOT (PN0+PN1+PN2+PN3+PN4)
__global__ __launch_bounds__(256) void prep_k(
    const float* __restrict__ x, const float* __restrict__ W_in,
    const float* __restrict__ W_xproj, const float* __restrict__ W_dt,
    const float* __restrict__ W_out,
    u16* __restrict__ x_bf, u16* __restrict__ Win_bf, u16* __restrict__ Wxp_bf,
    u16* __restrict__ Wdt_bf, u16* __restrict__ Wout_bf)
{
  int i = (blockIdx.x * 256 + threadIdx.x) * 4;   // all segment sizes are 4-aligned
  const float* src; u16* dst; bool pad = false; int local = i;
  if (local < PN0)            { src = x;       dst = x_bf; }
  else if ((local -= PN0) < PN1) { src = W_in;    dst = Win_bf; }
  else if ((local -= PN1) < PN2) { src = W_xproj; dst = Wxp_bf; pad = (local >> 11) >= 96; }
  else if ((local -= PN2) < PN3) { src = W_dt;    dst = Wdt_bf; }
  else if ((local -= PN3) < PN4) { src = W_out;   dst = Wout_bf; }
  else return;
  ushort4 o;
  if (pad) { o = (ushort4){0,0,0,0}; }
  else {
    const float4 v = *(const float4*)(src + local);
    o = (ushort4){ f2bf(v.x), f2bf(v.y), f2bf(v.z), f2bf(v.w) };
  }
  *(ushort4*)(dst + local) = o;
}

// ---------------- bf16 NT GEMM: C[M,N] = A[M,K] * B[N,K]^T ----------------
// KB = K-tile (32 or 64). LDS rows are KB bf16; 16B-chunk column swizzled by
// cc ^= row&(CPR-1) so ds_read_b128 lands at worst 2-way (free) bank overlap.
// EPI: 0=f32 store, 1=bf16 store, 2=softplus(acc+bias[col])->bf16, 3=acc+res f32,
//      4=f32 store into partial plane blockIdx.z (split-K; K range shifts by z)
template<int BM, int BN, int KB, int WTM, int WTN, int EPI>
__global__ __launch_bounds__(256) void gemm_nt(
    const u16* __restrict__ A, const u16* __restrict__ B,
    float* __restrict__ C, u16* __restrict__ Cb,
    const float* __restrict__ bias, const float* __restrict__ res,
    int kStart, int kEnd, int lda, int ldb, int ldc, size_t partStride)
{
  constexpr int CPR  = KB / 8;            // 16B chunks per LDS row
  constexpr int MASK = CPR - 1;
  constexpr int KSUB = KB / 32;           // 32-k MFMA sub-steps per tile
  constexpr int WAVES_N = BN / (16 * WTN);
  constexpr int ACH = BM * CPR;
  constexpr int BCH = BN * CPR;
  constexpr int ROUNDS = (ACH + BCH) / 256;

  __shared__ __align__(16) u16 lA[BM * KB];
  __shared__ __align__(16) u16 lB[BN * KB];

  const int tid  = threadIdx.x;
  const int w    = tid >> 6;
  const int lane = tid & 63;
  const int lrow = lane & 15;
  const int quad = lane >> 4;
  const int bm = blockIdx.y * BM;
  const int bn = blockIdx.x * BN;
  const int wave_m = (w / WAVES_N) * (16 * WTM);
  const int wave_n = (w % WAVES_N) * (16 * WTN);

  int kOff = 0;
  if constexpr (EPI == 4) kOff = blockIdx.z * (kEnd - kStart);

  f32x4 acc[WTM][WTN];
  #pragma unroll
  for (int mi = 0; mi < WTM; ++mi)
    #pragma unroll
    for (int ni = 0; ni < WTN; ++ni)
      acc[mi][ni] = (f32x4){0.f, 0.f, 0.f, 0.f};

  for (int k0 = kStart + kOff; k0 < kEnd + kOff; k0 += KB) {
    #pragma unroll
    for (int r = 0; r < ROUNDS; ++r) {
      const int c0 = r * 256 + w * 64;    // wave-uniform chunk base
      const int c  = c0 + lane;
      if (c0 < ACH) {
        const int row = c / CPR, cc = (c & MASK) ^ (row & MASK);
        async16(A + (size_t)(bm + row) * lda + k0 + cc * 8, &lA[c0 * 8]);
      } else {
        const int cb = c - ACH, c0b = c0 - ACH;
        const int row = cb / CPR, cc = (cb & MASK) ^ (row & MASK);
        async16(B + (size_t)(bn + row) * ldb + k0 + cc * 8, &lB[c0b * 8]);
      }
    }
    __syncthreads();   // drain global_load_lds + join

    #pragma unroll
    for (int s = 0; s < KSUB; ++s) {
      bf16x8 af[WTM], bfv[WTN];
      #pragma unroll
      for (int mi = 0; mi < WTM; ++mi) {
        const int R = wave_m + mi * 16 + lrow;
        af[mi] = *(const bf16x8*)&lA[R * KB + (((s * 4 + quad) ^ (R & MASK)) * 8)];
      }
      #pragma unroll
      for (int ni = 0; ni < WTN; ++ni) {
        const int R = wave_n + ni * 16 + lrow;
        bfv[ni] = *(const bf16x8*)&lB[R * KB + (((s * 4 + quad) ^ (R & MASK)) * 8)];
      }
      #pragma unroll
      for (int mi = 0; mi < WTM; ++mi)
        #pragma unroll
        for (int ni = 0; ni < WTN; ++ni)
          acc[mi][ni] = __builtin_amdgcn_mfma_f32_16x16x32_bf16(af[mi], bfv[ni], acc[mi][ni], 0, 0, 0);
    }
    __syncthreads();   // all waves done reading before next overwrite
  }

  #pragma unroll
  for (int mi = 0; mi < WTM; ++mi) {
    #pragma unroll
    for (int ni = 0; ni < WTN; ++ni) {
      const int col  = bn + wave_n + ni * 16 + lrow;
      const int row0 = bm + wave_m + mi * 16 + quad * 4;
      #pragma unroll
      for (int r = 0; r < 4; ++r) {
        float v = acc[mi][ni][r];
        const size_t idx = (size_t)(row0 + r) * ldc + col;
        if constexpr (EPI == 0) {
          C[idx] = v;
        } else if constexpr (EPI == 1) {
          Cb[idx] = f2bf(v);
        } else if constexpr (EPI == 2) {
          v += bias[col];
          v = (v > 20.f) ? v : log1pf(__expf(v));   // softplus
          Cb[idx] = f2bf(v);
        } else if constexpr (EPI == 3) {
          C[idx] = v + res[idx];
        } else {
          C[(size_t)blockIdx.z * partStride + idx] = v;
        }
      }
    }
  }
}

// ---------------- split-K reduce + bf16 convert (x_proj) ----------------
__global__ __launch_bounds__(256) void reduce_conv_k(
    const float* __restrict__ part, u16* __restrict__ dst)
{
  const int i = blockIdx.x * 256 + threadIdx.x;     // over NTOK*128
  float s = 0.f;
  #pragma unroll
  for (int p = 0; p < KSPLIT; ++p)
    s += part[(size_t)p * (NTOK * 128) + i];
  dst[i] = f2bf(s);
}

// ---------------- causal depthwise conv (D_CONV=4) + SiLU -> bf16 ----------------
// Sliding window: each thread handles 8 consecutive tokens x 4 channels.
#define CONV_T 8
__global__ __launch_bounds__(256) void conv_silu_k(
    const u16* __restrict__ xz, const float* __restrict__ Wc,
    const float* __restrict__ bc, u16* __restrict__ ub)
{
  const int tid = blockIdx.x * 256 + threadIdx.x;
  const int e   = (tid & 511) * 4;                  // channel group (consecutive lanes -> coalesced)
  const int tb  = tid >> 9;
  const int tok0 = tb * CONV_T;
  const int l0   = tok0 & (SEQ - 1);

  float4 wq[4];
  #pragma unroll
  for (int q = 0; q < 4; ++q) wq[q] = *(const float4*)(Wc + (e + q) * 4);
  const float4 bcv = *(const float4*)(bc + e);

  float p3[4], p2[4], p1[4];
  if (l0 == 0) {
    #pragma unroll
    for (int q = 0; q < 4; ++q) { p3[q] = 0.f; p2[q] = 0.f; p1[q] = 0.f; }
  } else {
    const ushort4 a = *(const ushort4*)(xz + (size_t)(tok0 - 3) * (2 * D_INNER) + e);
    const ushort4 b = *(const ushort4*)(xz + (size_t)(tok0 - 2) * (2 * D_INNER) + e);
    const ushort4 c = *(const ushort4*)(xz + (size_t)(tok0 - 1) * (2 * D_INNER) + e);
    p3[0]=bf2f(a.x); p3[1]=bf2f(a.y); p3[2]=bf2f(a.z); p3[3]=bf2f(a.w);
    p2[0]=bf2f(b.x); p2[1]=bf2f(b.y); p2[2]=bf2f(b.z); p2[3]=bf2f(b.w);
    p1[0]=bf2f(c.x); p1[1]=bf2f(c.y); p1[2]=bf2f(c.z); p1[3]=bf2f(c.w);
  }

  #pragma unroll
  for (int tt = 0; tt < CONV_T; ++tt) {
    const ushort4 xv = *(const ushort4*)(xz + (size_t)(tok0 + tt) * (2 * D_INNER) + e);
    float cur[4] = { bf2f(xv.x), bf2f(xv.y), bf2f(xv.z), bf2f(xv.w) };
    ushort4 o;
    u16* op = (u16*)&o;
    float a0 = ((const float*)&bcv)[0] + p3[0]*wq[0].x + p2[0]*wq[0].y + p1[0]*wq[0].z + cur[0]*wq[0].w;
    float a1 = ((const float*)&bcv)[1] + p3[1]*wq[1].x + p2[1]*wq[1].y + p1[1]*wq[1].z + cur[1]*wq[1].w;
    float a2 = ((const float*)&bcv)[2] + p3[2]*wq[2].x + p2[2]*wq[2].y + p1[2]*wq[2].z + cur[2]*wq[2].w;
    float a3 = ((const float*)&bcv)[3] + p3[3]*wq[3].x + p2[3]*wq[3].y + p1[3]*wq[3].z + cur[3]*wq[3].w;
    op[0] = f2bf(a0 / (1.f + __expf(-a0)));
    op[1] = f2bf(a1 / (1.f + __expf(-a1)));
    op[2] = f2bf(a2 / (1.f + __expf(-a2)));
    op[3] = f2bf(a3 / (1.f + __expf(-a3)));
    *(ushort4*)(ub + (size_t)(tok0 + tt) * D_INNER + e) = o;
    #pragma unroll
    for (int q = 0; q < 4; ++q) { p3[q] = p2[q]; p2[q] = p1[q]; p1[q] = cur[q]; }
  }
}

// ---------------- selective scan, chunk-parallel (3 passes) ----------------
// A_log = log(1..16) => A[n] = -(n+1) exactly; exp(dlt*A[n]) = q^(n+1), q=exp(-dlt).
// Runtime-checked fast path; slow path preserves generality.

// Pass 1: local scan with h=0 -> S[b,c,e,16], sum of delta -> sumd[b,c,e]
__global__ __launch_bounds__(256) void scan_p1(
    const u16* __restrict__ delta, const u16* __restrict__ ub,
    const u16* __restrict__ xdb, const float* __restrict__ A_log,
    float* __restrict__ S, float* __restrict__ sumd)
{
  const int e = blockIdx.x * 256 + threadIdx.x;
  const int c = blockIdx.y;
  const int b = blockIdx.z;
  float A[16], h[16];
  bool fast = true;
  #pragma unroll
  for (int n = 0; n < 16; ++n) {
    A[n] = -__expf(A_log[e * 16 + n]);
    fast = fast && (fabsf(A[n] + (float)(n + 1)) < 1e-3f);
    h[n] = 0.f;
  }
  float sd = 0.f;
  const int t0 = c * TCHUNK;
  #pragma unroll 2
  for (int t = 0; t < TCHUNK; ++t) {
    const size_t g = (size_t)(b * SEQ + t0 + t);
    const float dlt = bf2f(delta[g * D_INNER + e]);
    const float ut  = bf2f(ub[g * D_INNER + e]);
    float Bv[16];
    const u16* bp = xdb + g * 128 + DT_RANK;
    unpack8(*(const uint4*)bp, Bv);
    unpack8(*(const uint4*)(bp + 8), Bv + 8);
    sd += dlt;
    const float dbu = dlt * ut;
    float dA[16];
    if (fast) {
      const float q = __expf(-dlt);
      float p = 1.f;
      #pragma unroll
      for (int n = 0; n < 16; ++n) { p *= q; dA[n] = p; }
    } else {
      #pragma unroll
      for (int n = 0; n < 16; ++n) dA[n] = __expf(dlt * A[n]);
    }
    #pragma unroll
    for (int n = 0; n < 16; ++n)
      h[n] = dA[n] * h[n] + dbu * Bv[n];
  }
  const size_t idx = ((size_t)(b * NCHUNK + c) * D_INNER + e);
  #pragma unroll
  for (int q = 0; q < 4; ++q)
    *(f32x4*)&S[idx * 16 + q * 4] = (f32x4){h[q*4], h[q*4+1], h[q*4+2], h[q*4+3]};
  sumd[idx] = sd;
}

// Pass 2: sequential over chunks -> h_init[b,c,e,16]
__global__ __launch_bounds__(256) void scan_p2(
    const float* __restrict__ S, const float* __restrict__ sumd,
    const float* __restrict__ A_log, float* __restrict__ hinit)
{
  const int tid = blockIdx.x * 256 + threadIdx.x;   // 65536
  const int n = tid & 15;
  const int e = (tid >> 4) & (D_INNER - 1);
  const int b = tid >> 15;
  const float An = -__expf(A_log[e * 16 + n]);
  float h = 0.f;
  size_t idx = (size_t)b * NCHUNK * D_INNER + e;
  float s_cur  = S[idx * 16 + n];
  float sd_cur = sumd[idx];
  for (int c = 0; c < NCHUNK; ++c) {
    hinit[idx * 16 + n] = h;
    float s_nxt = 0.f, sd_nxt = 0.f;
    if (c + 1 < NCHUNK) {
      const size_t idx2 = idx + D_INNER;
      s_nxt  = S[idx2 * 16 + n];
      sd_nxt = sumd[idx2];
    }
    h = __expf(An * sd_cur) * h + s_cur;
    s_cur = s_nxt; sd_cur = sd_nxt;
    idx += D_INNER;
  }
}

// Pass 3: recompute chunk scan from h_init, fused y-dot + skip + gate -> yg (bf16)
__global__ __launch_bounds__(256) void scan_p3(
    const u16* __restrict__ delta, const u16* __restrict__ ub,
    const u16* __restrict__ xdb, const u16* __restrict__ xz,
    const float* __restrict__ A_log, const float* __restrict__ D_skip,
    const float* __restrict__ hinit, u16* __restrict__ yg)
{
  const int e = blockIdx.x * 256 + threadIdx.x;
  const int c = blockIdx.y;
  const int b = blockIdx.z;
  const size_t idx = ((size_t)(b * NCHUNK + c) * D_INNER + e);
  float A[16], h[16];
  bool fast = true;
  #pragma unroll
  for (int n = 0; n < 16; ++n) {
    A[n] = -__expf(A_log[e * 16 + n]);
    fast = fast && (fabsf(A[n] + (float)(n + 1)) < 1e-3f);
  }
  #pragma unroll
  for (int q = 0; q < 4; ++q) {
    f32x4 v = *(const f32x4*)&hinit[idx * 16 + q * 4];
    h[q*4] = v[0]; h[q*4+1] = v[1]; h[q*4+2] = v[2]; h[q*4+3] = v[3];
  }
  const float De = D_skip[e];
  const int t0 = c * TCHUNK;
  #pragma unroll 2
  for (int t = 0; t < TCHUNK; ++t) {
    const size_t g = (size_t)(b * SEQ + t0 + t);
    const float dlt = bf2f(delta[g * D_INNER + e]);
    const float ut  = bf2f(ub[g * D_INNER + e]);
    const float z   = bf2f(xz[g * (2 * D_INNER) + D_INNER + e]);
    float Bv[16], Cv[16];
    const u16* bp = xdb + g * 128 + DT_RANK;
    unpack8(*(const uint4*)bp, Bv);
    unpack8(*(const uint4*)(bp + 8), Bv + 8);
    unpack8(*(const uint4*)(bp + 16), Cv);
    unpack8(*(const uint4*)(bp + 24), Cv + 8);
    const float dbu = dlt * ut;
    float dA[16];
    if (fast) {
      const float q = __expf(-dlt);
      float p = 1.f;
      #pragma unroll
      for (int n = 0; n < 16; ++n) { p *= q; dA[n] = p; }
    } else {
      #pragma unroll
      for (int n = 0; n < 16; ++n) dA[n] = __expf(dlt * A[n]);
    }
    float y = 0.f;
    #pragma unroll
    for (int n = 0; n < 16; ++n) {
      h[n] = dA[n] * h[n] + dbu * Bv[n];
      y += h[n] * Cv[n];
    }
    y += ut * De;
    const float gt = z / (1.f + __expf(-z));
    yg[g * D_INNER + e] = f2bf(y * gt);
  }
}

// ---------------- LayerNorm, one block per token ----------------
__global__ __launch_bounds__(256) void ln_k(const float* __restrict__ pre,
                                            const float* __restrict__ gamma,
                                            const float* __restrict__ beta,
                                            float* __restrict__ out)
{
  const int tok = blockIdx.x;
  const int t   = threadIdx.x;
  const float* row = pre + (size_t)tok * D_MODEL;
  float v[4], s = 0.f, s2 = 0.f;
  #pragma unroll
  for (int i = 0; i < 4; ++i) {
    v[i] = row[t + i * 256];
    s += v[i]; s2 += v[i] * v[i];
  }
  #pragma unroll
  for (int off = 32; off >= 1; off >>= 1) {
    s  += __shfl_xor(s,  off);
    s2 += __shfl_xor(s2, off);
  }
  __shared__ float red[8];
  if ((t & 63) == 0) { red[t >> 6] = s; red[4 + (t >> 6)] = s2; }
  __syncthreads();
  if (t == 0) {
    const float ts  = red[0] + red[1] + red[2] + red[3];
    const float ts2 = red[4] + red[5] + red[6] + red[7];
    const float mu  = ts * (1.f / D_MODEL);
    const float var = ts2 * (1.f / D_MODEL) - mu * mu;
    red[0] = mu; red[1] = rsqrtf(var + LN_EPSF);
  }
  __syncthreads();
  const float mu = red[0], rv = red[1];
  #pragma unroll
  for (int i = 0; i < 4; ++i) {
    const int c = t + i * 256;
    out[(size_t)tok * D_MODEL + c] = (v[i] - mu) * rv * gamma[c] + beta[c];
  }
}

// ---------------- host launch ----------------
extern "C" void kernel_launch(void* const* d_in, const int* in_sizes, int n_in,
                              void* d_out, int out_size, void* d_ws, size_t ws_size,
                              hipStream_t stream) {
  const float* x       = (const float*)d_in[0];
  const float* W_in    = (const float*)d_in[1];
  const float* W_conv  = (const float*)d_in[2];
  const float* b_conv  = (const float*)d_in[3];
  const float* W_xproj = (const float*)d_in[4];
  const float* W_dt    = (const float*)d_in[5];
  const float* b_dt    = (const float*)d_in[6];
  const float* A_log   = (const float*)d_in[7];
  const float* D_skip  = (const float*)d_in[8];
  const float* W_out   = (const float*)d_in[9];
  const float* gamma   = (const float*)d_in[10];
  const float* beta    = (const float*)d_in[11];
  float* out = (float*)d_out;

  // workspace carve-up (256B aligned)
  char* ws = (char*)d_ws;
  size_t used = 0;
  auto alloc = [&](size_t bytes) -> char* {
    char* p = ws + used;
    used += (bytes + 255) & ~(size_t)255;
    return p;
  };
  u16* xz_bf     = (u16*)alloc((size_t)NTOK * 2 * D_INNER * 2);     // 33.5 MB
  float* pre     = (float*)alloc((size_t)NTOK * D_MODEL * 4);       // 16.8 MB; alias S
  char*  xw_reg  = alloc((size_t)NTOK * D_MODEL * 2 + (size_t)2 * D_INNER * D_MODEL * 2);
                                                                    // x_bf+Win_bf; alias hinit
  u16* u_bf      = (u16*)alloc((size_t)NTOK * D_INNER * 2);         // 16.8 MB
  u16* delta_bf  = (u16*)alloc((size_t)NTOK * D_INNER * 2);         // 16.8 MB
  u16* xdb_bf    = (u16*)alloc((size_t)NTOK * 128 * 2);             // 1 MB (96 padded to 128)
  u16* Wxp_bf    = (u16*)alloc((size_t)128 * D_INNER * 2);          // 0.5 MB
  u16* Wdt_bf    = (u16*)alloc((size_t)D_INNER * DT_RANK * 2);      // 0.26 MB
  u16* Wout_bf   = (u16*)alloc((size_t)D_MODEL * D_INNER * 2);      // 4.2 MB
  u16* yg_bf     = (u16*)alloc((size_t)NTOK * D_INNER * 2);         // 16.8 MB
  float* sumd    = (float*)alloc((size_t)NBATCH * NCHUNK * D_INNER * 4); // 1 MB
  float* xdb_part= (float*)alloc((size_t)KSPLIT * NTOK * 128 * 4);  // 16.8 MB

  // aliases (time-disjoint usage)
  u16* x_bf    = (u16*)xw_reg;                                    // dead after GEMM1
  u16* Win_bf  = (u16*)(xw_reg + (size_t)NTOK * D_MODEL * 2);     // dead after GEMM1
  float* S     = pre;                                             // pre written at stage 6
  float* hinit = (float*)xw_reg;                                  // 16.8 MB, after GEMM1

  if (ws_size < used) {   // signal: NaN output (insufficient workspace)
    hipMemsetAsync(d_out, 0xFF, (size_t)out_size * 4, stream);
    return;
  }

  const dim3 blk(256);

  // 0) all f32->bf16 conversions in one kernel (4 elems/thread)
  prep_k<<<(PTOT / 4 + 255) / 256, blk, 0, stream>>>(
      x, W_in, W_xproj, W_dt, W_out, x_bf, Win_bf, Wxp_bf, Wdt_bf, Wout_bf);

  // 1) in_proj: xz[4096,4096] = x[4096,1024] * W_in[4096,1024]^T  (bf16 out, BK=64)
  gemm_nt<128,128,64,4,4,1><<<dim3((2*D_INNER)/128, NTOK/128), blk, 0, stream>>>(
      x_bf, Win_bf, nullptr, xz_bf, nullptr, nullptr,
      0, D_MODEL, D_MODEL, D_MODEL, 2*D_INNER, 0);

  // 2) causal depthwise conv + silu -> u (bf16): 8 tokens x 4 channels per thread
  conv_silu_k<<<(NTOK / CONV_T) * (D_INNER / 4) / 256, blk, 0, stream>>>(
      xz_bf, W_conv, b_conv, u_bf);

  // 3) x_proj split-K=8: partials[8][4096][128] = u * W_xproj^T  (BK=32)
  gemm_nt<64,128,32,1,8,4><<<dim3(1, NTOK/64, KSPLIT), blk, 0, stream>>>(
      u_bf, Wxp_bf, xdb_part, nullptr, nullptr, nullptr,
      0, D_INNER / KSPLIT, D_INNER, D_INNER, 128, (size_t)NTOK * 128);
  reduce_conv_k<<<(NTOK * 128) / 256, blk, 0, stream>>>(xdb_part, xdb_bf);

  // 4) dt_proj + bias + softplus: delta[4096,2048] -> bf16  (BK=64: single K-iter)
  gemm_nt<128,128,64,4,4,2><<<dim3(D_INNER/128, NTOK/128), blk, 0, stream>>>(
      xdb_bf, Wdt_bf, nullptr, delta_bf, b_dt, nullptr,
      0, DT_RANK, 128, DT_RANK, D_INNER, 0);

  // 5) chunk-parallel selective scan + skip + gate -> yg (bf16)
  scan_p1<<<dim3(D_INNER/256, NCHUNK, NBATCH), blk, 0, stream>>>(
      delta_bf, u_bf, xdb_bf, A_log, S, sumd);
  scan_p2<<<(NBATCH * D_INNER * D_STATE) / 256, blk, 0, stream>>>(
      S, sumd, A_log, hinit);
  scan_p3<<<dim3(D_INNER/256, NCHUNK, NBATCH), blk, 0, stream>>>(
      delta_bf, u_bf, xdb_bf, xz_bf, A_log, D_skip, hinit, yg_bf);

  // 6) out_proj + residual: pre[4096,1024] = yg * W_out^T + x  (128x64 tiles, BK=64)
  gemm_nt<128,64,64,4,2,3><<<dim3(D_MODEL/64, NTOK/128), blk, 0, stream>>>(
      yg_bf, Wout_bf, pre, nullptr, nullptr, x,
      0, D_INNER, D_INNER, D_INNER, D_MODEL, 0);

  // 7) LayerNorm
  ln_k<<<NTOK, blk, 0, stream>>>(pre, gamma, beta, out);
}

// Round 8
// 309.666 us; speedup vs baseline: 1.2580x; 1.0079x over previous
//
#include <hip/hip_runtime.h>
#include <cstdint>
#include <cstddef>

// ---------------- problem constants ----------------
#define D_MODEL   1024
#define D_STATE   16
#define D_CONV    4
#define D_INNER   2048
#define DT_RANK   64
#define NBATCH    2
#define SEQ       2048
#define NTOK      (NBATCH*SEQ)     // 4096 tokens
#define LN_EPSF   1e-5f
#define NCHUNK    64
#define TCHUNK    32               // SEQ / NCHUNK
#define KSPLIT    8                // x_proj split-K factor

typedef unsigned short u16;
typedef __bf16 bf16x8 __attribute__((ext_vector_type(8)));
typedef float  f32x4  __attribute__((ext_vector_type(4)));

__device__ __forceinline__ u16 f2bf(float f) {
  unsigned u = __float_as_uint(f);
  u += 0x7fffu + ((u >> 16) & 1u);          // round-to-nearest-even
  return (u16)(u >> 16);
}
__device__ __forceinline__ float bf2f(u16 v) {
  return __uint_as_float(((unsigned)v) << 16);
}
// unpack 8 bf16 (packed in uint4) -> 8 floats
__device__ __forceinline__ void unpack8(uint4 v, float* f) {
  f[0] = __uint_as_float(v.x << 16); f[1] = __uint_as_float(v.x & 0xffff0000u);
  f[2] = __uint_as_float(v.y << 16); f[3] = __uint_as_float(v.y & 0xffff0000u);
  f[4] = __uint_as_float(v.z << 16); f[5] = __uint_as_float(v.z & 0xffff0000u);
  f[6] = __uint_as_float(v.w << 16); f[7] = __uint_as_float(v.w & 0xffff0000u);
}

// async global->LDS, 16B per lane; lds dest must be wave-uniform base (+lane*16)
__device__ __forceinline__ void async16(const u16* g, u16* l) {
  __builtin_amdgcn_global_load_lds(
      (const __attribute__((address_space(1))) unsigned*)g,
      (__attribute__((address_space(3))) unsigned*)l, 16, 0, 0);
}

// ---------------- fused prep: all f32->bf16 conversions, 4 elems/thread ----------------
#define PN0 (NTOK*D_MODEL)          // x
#define PN1 (2*D_INNER*D_MODEL)     // W_in
#define PN2 (128*D_INNER)           // W_xproj (padded 96->128 rows)
#define PN3 (D_INNER*DT_RANK)       // W_dt
#define PN4 (D_MODEL*D_INNER)       // W_out
#define PTOT (PN0+PN1+PN2+PN3+PN4)
__global__ __launch_bounds__(256) void prep_k(
    const float* __restrict__ x, const float* __restrict__ W_in,
    const float* __restrict__ W_xproj, const float* __restrict__ W_dt,
    const float* __restrict__ W_out,
    u16* __restrict__ x_bf, u16* __restrict__ Win_bf, u16* __restrict__ Wxp_bf,
    u16* __restrict__ Wdt_bf, u16* __restrict__ Wout_bf)
{
  int i = (blockIdx.x * 256 + threadIdx.x) * 4;   // all segment sizes are 4-aligned
  const float* src; u16* dst; bool pad = false; int local = i;
  if (local < PN0)            { src = x;       dst = x_bf; }
  else if ((local -= PN0) < PN1) { src = W_in;    dst = Win_bf; }
  else if ((local -= PN1) < PN2) { src = W_xproj; dst = Wxp_bf; pad = (local >> 11) >= 96; }
  else if ((local -= PN2) < PN3) { src = W_dt;    dst = Wdt_bf; }
  else if ((local -= PN3) < PN4) { src = W_out;   dst = Wout_bf; }
  else return;
  ushort4 o;
  if (pad) { o = (ushort4){0,0,0,0}; }
  else {
    const float4 v = *(const float4*)(src + local);
    o = (ushort4){ f2bf(v.x), f2bf(v.y), f2bf(v.z), f2bf(v.w) };
  }
  *(ushort4*)(dst + local) = o;
}

// ---------------- bf16 NT GEMM: C[M,N] = A[M,K] * B[N,K]^T ----------------
// KB = K-tile (32 or 64). LDS rows are KB bf16; 16B-chunk column swizzled by
// cc ^= row&(CPR-1) so ds_read_b128 lands at worst 2-way (free) bank overlap.
// SWAPG: bm from blockIdx.x, bn from blockIdx.y — puts all col-blocks of one
// row-panel on one XCD (ids congruent mod 8) so the A panel is L2-resident.
// EPI: 0=f32 store, 1=bf16 store, 2=softplus(acc+bias[col])->bf16, 3=acc+res f32,
//      4=f32 store into partial plane blockIdx.z (split-K; K range shifts by z)
template<int BM, int BN, int KB, int WTM, int WTN, int EPI, int SWAPG>
__global__ __launch_bounds__(256) void gemm_nt(
    const u16* __restrict__ A, const u16* __restrict__ B,
    float* __restrict__ C, u16* __restrict__ Cb,
    const float* __restrict__ bias, const float* __restrict__ res,
    int kStart, int kEnd, int lda, int ldb, int ldc, size_t partStride)
{
  constexpr int CPR  = KB / 8;            // 16B chunks per LDS row
  constexpr int MASK = CPR - 1;
  constexpr int KSUB = KB / 32;           // 32-k MFMA sub-steps per tile
  constexpr int WAVES_N = BN / (16 * WTN);
  constexpr int ACH = BM * CPR;
  constexpr int BCH = BN * CPR;
  constexpr int ROUNDS = (ACH + BCH) / 256;

  __shared__ __align__(16) u16 lA[BM * KB];
  __shared__ __align__(16) u16 lB[BN * KB];

  const int tid  = threadIdx.x;
  const int w    = tid >> 6;
  const int lane = tid & 63;
  const int lrow = lane & 15;
  const int quad = lane >> 4;
  const int bm = (SWAPG ? blockIdx.x : blockIdx.y) * BM;
  const int bn = (SWAPG ? blockIdx.y : blockIdx.x) * BN;
  const int wave_m = (w / WAVES_N) * (16 * WTM);
  const int wave_n = (w % WAVES_N) * (16 * WTN);

  int kOff = 0;
  if constexpr (EPI == 4) kOff = blockIdx.z * (kEnd - kStart);

  f32x4 acc[WTM][WTN];
  #pragma unroll
  for (int mi = 0; mi < WTM; ++mi)
    #pragma unroll
    for (int ni = 0; ni < WTN; ++ni)
      acc[mi][ni] = (f32x4){0.f, 0.f, 0.f, 0.f};

  for (int k0 = kStart + kOff; k0 < kEnd + kOff; k0 += KB) {
    #pragma unroll
    for (int r = 0; r < ROUNDS; ++r) {
      const int c0 = r * 256 + w * 64;    // wave-uniform chunk base
      const int c  = c0 + lane;
      if (c0 < ACH) {
        const int row = c / CPR, cc = (c & MASK) ^ (row & MASK);
        async16(A + (size_t)(bm + row) * lda + k0 + cc * 8, &lA[c0 * 8]);
      } else {
        const int cb = c - ACH, c0b = c0 - ACH;
        const int row = cb / CPR, cc = (cb & MASK) ^ (row & MASK);
        async16(B + (size_t)(bn + row) * ldb + k0 + cc * 8, &lB[c0b * 8]);
      }
    }
    __syncthreads();   // drain global_load_lds + join

    #pragma unroll
    for (int s = 0; s < KSUB; ++s) {
      bf16x8 af[WTM], bfv[WTN];
      #pragma unroll
      for (int mi = 0; mi < WTM; ++mi) {
        const int R = wave_m + mi * 16 + lrow;
        af[mi] = *(const bf16x8*)&lA[R * KB + (((s * 4 + quad) ^ (R & MASK)) * 8)];
      }
      #pragma unroll
      for (int ni = 0; ni < WTN; ++ni) {
        const int R = wave_n + ni * 16 + lrow;
        bfv[ni] = *(const bf16x8*)&lB[R * KB + (((s * 4 + quad) ^ (R & MASK)) * 8)];
      }
      #pragma unroll
      for (int mi = 0; mi < WTM; ++mi)
        #pragma unroll
        for (int ni = 0; ni < WTN; ++ni)
          acc[mi][ni] = __builtin_amdgcn_mfma_f32_16x16x32_bf16(af[mi], bfv[ni], acc[mi][ni], 0, 0, 0);
    }
    __syncthreads();   // all waves done reading before next overwrite
  }

  #pragma unroll
  for (int mi = 0; mi < WTM; ++mi) {
    #pragma unroll
    for (int ni = 0; ni < WTN; ++ni) {
      const int col  = bn + wave_n + ni * 16 + lrow;
      const int row0 = bm + wave_m + mi * 16 + quad * 4;
      #pragma unroll
      for (int r = 0; r < 4; ++r) {
        float v = acc[mi][ni][r];
        const size_t idx = (size_t)(row0 + r) * ldc + col;
        if constexpr (EPI == 0) {
          C[idx] = v;
        } else if constexpr (EPI == 1) {
          Cb[idx] = f2bf(v);
        } else if constexpr (EPI == 2) {
          v += bias[col];
          v = (v > 20.f) ? v : log1pf(__expf(v));   // softplus
          Cb[idx] = f2bf(v);
        } else if constexpr (EPI == 3) {
          C[idx] = v + res[idx];
        } else {
          C[(size_t)blockIdx.z * partStride + idx] = v;
        }
      }
    }
  }
}

// ---------------- split-K reduce + bf16 convert (x_proj) ----------------
__global__ __launch_bounds__(256) void reduce_conv_k(
    const float* __restrict__ part, u16* __restrict__ dst)
{
  const int i = blockIdx.x * 256 + threadIdx.x;     // over NTOK*128
  float s = 0.f;
  #pragma unroll
  for (int p = 0; p < KSPLIT; ++p)
    s += part[(size_t)p * (NTOK * 128) + i];
  dst[i] = f2bf(s);
}

// ---------------- causal depthwise conv (D_CONV=4) + SiLU -> bf16 ----------------
// Sliding window: each thread handles 8 consecutive tokens x 4 channels.
#define CONV_T 8
__global__ __launch_bounds__(256) void conv_silu_k(
    const u16* __restrict__ xz, const float* __restrict__ Wc,
    const float* __restrict__ bc, u16* __restrict__ ub)
{
  const int tid = blockIdx.x * 256 + threadIdx.x;
  const int e   = (tid & 511) * 4;                  // channel group (consecutive lanes -> coalesced)
  const int tb  = tid >> 9;
  const int tok0 = tb * CONV_T;
  const int l0   = tok0 & (SEQ - 1);

  float4 wq[4];
  #pragma unroll
  for (int q = 0; q < 4; ++q) wq[q] = *(const float4*)(Wc + (e + q) * 4);
  const float4 bcv = *(const float4*)(bc + e);

  float p3[4], p2[4], p1[4];
  if (l0 == 0) {
    #pragma unroll
    for (int q = 0; q < 4; ++q) { p3[q] = 0.f; p2[q] = 0.f; p1[q] = 0.f; }
  } else {
    const ushort4 a = *(const ushort4*)(xz + (size_t)(tok0 - 3) * (2 * D_INNER) + e);
    const ushort4 b = *(const ushort4*)(xz + (size_t)(tok0 - 2) * (2 * D_INNER) + e);
    const ushort4 c = *(const ushort4*)(xz + (size_t)(tok0 - 1) * (2 * D_INNER) + e);
    p3[0]=bf2f(a.x); p3[1]=bf2f(a.y); p3[2]=bf2f(a.z); p3[3]=bf2f(a.w);
    p2[0]=bf2f(b.x); p2[1]=bf2f(b.y); p2[2]=bf2f(b.z); p2[3]=bf2f(b.w);
    p1[0]=bf2f(c.x); p1[1]=bf2f(c.y); p1[2]=bf2f(c.z); p1[3]=bf2f(c.w);
  }

  #pragma unroll
  for (int tt = 0; tt < CONV_T; ++tt) {
    const ushort4 xv = *(const ushort4*)(xz + (size_t)(tok0 + tt) * (2 * D_INNER) + e);
    float cur[4] = { bf2f(xv.x), bf2f(xv.y), bf2f(xv.z), bf2f(xv.w) };
    ushort4 o;
    u16* op = (u16*)&o;
    float a0 = ((const float*)&bcv)[0] + p3[0]*wq[0].x + p2[0]*wq[0].y + p1[0]*wq[0].z + cur[0]*wq[0].w;
    float a1 = ((const float*)&bcv)[1] + p3[1]*wq[1].x + p2[1]*wq[1].y + p1[1]*wq[1].z + cur[1]*wq[1].w;
    float a2 = ((const float*)&bcv)[2] + p3[2]*wq[2].x + p2[2]*wq[2].y + p1[2]*wq[2].z + cur[2]*wq[2].w;
    float a3 = ((const float*)&bcv)[3] + p3[3]*wq[3].x + p2[3]*wq[3].y + p1[3]*wq[3].z + cur[3]*wq[3].w;
    op[0] = f2bf(a0 / (1.f + __expf(-a0)));
    op[1] = f2bf(a1 / (1.f + __expf(-a1)));
    op[2] = f2bf(a2 / (1.f + __expf(-a2)));
    op[3] = f2bf(a3 / (1.f + __expf(-a3)));
    *(ushort4*)(ub + (size_t)(tok0 + tt) * D_INNER + e) = o;
    #pragma unroll
    for (int q = 0; q < 4; ++q) { p3[q] = p2[q]; p2[q] = p1[q]; p1[q] = cur[q]; }
  }
}

// ---------------- selective scan, chunk-parallel (3 passes) ----------------
// A_log = log(1..16) => A[n] = -(n+1) exactly; exp(dlt*A[n]) = q^(n+1), q=exp(-dlt).
// Runtime-checked fast path; slow path preserves generality.
// S/hinit layout: [b][c][q][e][r] with n = q*4+r  (plane = D_INNER*4 floats)
// -> every S/hinit access is a fully-coalesced f32x4 per lane.
#define SPLANE (D_INNER * 4)

// Pass 1: local scan with h=0 -> S, sum of delta -> sumd[b,c,e]
__global__ __launch_bounds__(256) void scan_p1(
    const u16* __restrict__ delta, const u16* __restrict__ ub,
    const u16* __restrict__ xdb, const float* __restrict__ A_log,
    float* __restrict__ S, float* __restrict__ sumd)
{
  const int e = blockIdx.x * 256 + threadIdx.x;
  const int c = blockIdx.y;
  const int b = blockIdx.z;
  float A[16], h[16];
  bool fast = true;
  #pragma unroll
  for (int n = 0; n < 16; ++n) {
    A[n] = -__expf(A_log[e * 16 + n]);
    fast = fast && (fabsf(A[n] + (float)(n + 1)) < 1e-3f);
    h[n] = 0.f;
  }
  float sd = 0.f;
  const int t0 = c * TCHUNK;
  #pragma unroll 2
  for (int t = 0; t < TCHUNK; ++t) {
    const size_t g = (size_t)(b * SEQ + t0 + t);
    const float dlt = bf2f(delta[g * D_INNER + e]);
    const float ut  = bf2f(ub[g * D_INNER + e]);
    float Bv[16];
    const u16* bp = xdb + g * 128 + DT_RANK;
    unpack8(*(const uint4*)bp, Bv);
    unpack8(*(const uint4*)(bp + 8), Bv + 8);
    sd += dlt;
    const float dbu = dlt * ut;
    float dA[16];
    if (fast) {
      const float q = __expf(-dlt);
      float p = 1.f;
      #pragma unroll
      for (int n = 0; n < 16; ++n) { p *= q; dA[n] = p; }
    } else {
      #pragma unroll
      for (int n = 0; n < 16; ++n) dA[n] = __expf(dlt * A[n]);
    }
    #pragma unroll
    for (int n = 0; n < 16; ++n)
      h[n] = dA[n] * h[n] + dbu * Bv[n];
  }
  const size_t sbase = ((size_t)(b * NCHUNK + c) * 4) * SPLANE + e * 4;
  #pragma unroll
  for (int q = 0; q < 4; ++q)
    *(f32x4*)&S[sbase + (size_t)q * SPLANE] = (f32x4){h[q*4], h[q*4+1], h[q*4+2], h[q*4+3]};
  sumd[(size_t)(b * NCHUNK + c) * D_INNER + e] = sd;
}

// Pass 2: sequential over chunks -> h_init (same layout as S)
// block: wave = q (n-group), lane: e_lo = lane>>2, r = lane&3 -> coalesced planes
__global__ __launch_bounds__(256) void scan_p2(
    const float* __restrict__ S, const float* __restrict__ sumd,
    const float* __restrict__ A_log, float* __restrict__ hinit)
{
  const int q    = threadIdx.x >> 6;
  const int lane = threadIdx.x & 63;
  const int e    = blockIdx.x * 16 + (lane >> 2);
  const int r    = lane & 3;
  const int b    = blockIdx.y;
  const int n    = q * 4 + r;
  const float An = -__expf(A_log[e * 16 + n]);
  float h = 0.f;
  size_t sidx = ((size_t)(b * NCHUNK) * 4 + q) * SPLANE + e * 4 + r;
  size_t didx = (size_t)(b * NCHUNK) * D_INNER + e;
  float s_cur  = S[sidx];
  float sd_cur = sumd[didx];
  for (int c = 0; c < NCHUNK; ++c) {
    hinit[sidx] = h;
    float s_nxt = 0.f, sd_nxt = 0.f;
    if (c + 1 < NCHUNK) {
      s_nxt  = S[sidx + 4 * SPLANE];
      sd_nxt = sumd[didx + D_INNER];
    }
    h = __expf(An * sd_cur) * h + s_cur;
    s_cur = s_nxt; sd_cur = sd_nxt;
    sidx += 4 * SPLANE;
    didx += D_INNER;
  }
}

// Pass 3: recompute chunk scan from h_init, fused y-dot + skip + gate -> yg (bf16)
__global__ __launch_bounds__(256) void scan_p3(
    const u16* __restrict__ delta, const u16* __restrict__ ub,
    const u16* __restrict__ xdb, const u16* __restrict__ xz,
    const float* __restrict__ A_log, const float* __restrict__ D_skip,
    const float* __restrict__ hinit, u16* __restrict__ yg)
{
  const int e = blockIdx.x * 256 + threadIdx.x;
  const int c = blockIdx.y;
  const int b = blockIdx.z;
  float A[16], h[16];
  bool fast = true;
  #pragma unroll
  for (int n = 0; n < 16; ++n) {
    A[n] = -__expf(A_log[e * 16 + n]);
    fast = fast && (fabsf(A[n] + (float)(n + 1)) < 1e-3f);
  }
  const size_t sbase = ((size_t)(b * NCHUNK + c) * 4) * SPLANE + e * 4;
  #pragma unroll
  for (int q = 0; q < 4; ++q) {
    f32x4 v = *(const f32x4*)&hinit[sbase + (size_t)q * SPLANE];
    h[q*4] = v[0]; h[q*4+1] = v[1]; h[q*4+2] = v[2]; h[q*4+3] = v[3];
  }
  const float De = D_skip[e];
  const int t0 = c * TCHUNK;
  #pragma unroll 2
  for (int t = 0; t < TCHUNK; ++t) {
    const size_t g = (size_t)(b * SEQ + t0 + t);
    const float dlt = bf2f(delta[g * D_INNER + e]);
    const float ut  = bf2f(ub[g * D_INNER + e]);
    const float z   = bf2f(xz[g * (2 * D_INNER) + D_INNER + e]);
    float Bv[16], Cv[16];
    const u16* bp = xdb + g * 128 + DT_RANK;
    unpack8(*(const uint4*)bp, Bv);
    unpack8(*(const uint4*)(bp + 8), Bv + 8);
    unpack8(*(const uint4*)(bp + 16), Cv);
    unpack8(*(const uint4*)(bp + 24), Cv + 8);
    const float dbu = dlt * ut;
    float dA[16];
    if (fast) {
      const float q = __expf(-dlt);
      float p = 1.f;
      #pragma unroll
      for (int n = 0; n < 16; ++n) { p *= q; dA[n] = p; }
    } else {
      #pragma unroll
      for (int n = 0; n < 16; ++n) dA[n] = __expf(dlt * A[n]);
    }
    float y = 0.f;
    #pragma unroll
    for (int n = 0; n < 16; ++n) {
      h[n] = dA[n] * h[n] + dbu * Bv[n];
      y += h[n] * Cv[n];
    }
    y += ut * De;
    const float gt = z / (1.f + __expf(-z));
    yg[g * D_INNER + e] = f2bf(y * gt);
  }
}

// ---------------- LayerNorm, one block per token ----------------
__global__ __launch_bounds__(256) void ln_k(const float* __restrict__ pre,
                                            const float* __restrict__ gamma,
                                            const float* __restrict__ beta,
                                            float* __restrict__ out)
{
  const int tok = blockIdx.x;
  const int t   = threadIdx.x;
  const float* row = pre + (size_t)tok * D_MODEL;
  float v[4], s = 0.f, s2 = 0.f;
  #pragma unroll
  for (int i = 0; i < 4; ++i) {
    v[i] = row[t + i * 256];
    s += v[i]; s2 += v[i] * v[i];
  }
  #pragma unroll
  for (int off = 32; off >= 1; off >>= 1) {
    s  += __shfl_xor(s,  off);
    s2 += __shfl_xor(s2, off);
  }
  __shared__ float red[8];
  if ((t & 63) == 0) { red[t >> 6] = s; red[4 + (t >> 6)] = s2; }
  __syncthreads();
  if (t == 0) {
    const float ts  = red[0] + red[1] + red[2] + red[3];
    const float ts2 = red[4] + red[5] + red[6] + red[7];
    const float mu  = ts * (1.f / D_MODEL);
    const float var = ts2 * (1.f / D_MODEL) - mu * mu;
    red[0] = mu; red[1] = rsqrtf(var + LN_EPSF);
  }
  __syncthreads();
  const float mu = red[0], rv = red[1];
  #pragma unroll
  for (int i = 0; i < 4; ++i) {
    const int c = t + i * 256;
    out[(size_t)tok * D_MODEL + c] = (v[i] - mu) * rv * gamma[c] + beta[c];
  }
}

// ---------------- host launch ----------------
extern "C" void kernel_launch(void* const* d_in, const int* in_sizes, int n_in,
                              void* d_out, int out_size, void* d_ws, size_t ws_size,
                              hipStream_t stream) {
  const float* x       = (const float*)d_in[0];
  const float* W_in    = (const float*)d_in[1];
  const float* W_conv  = (const float*)d_in[2];
  const float* b_conv  = (const float*)d_in[3];
  const float* W_xproj = (const float*)d_in[4];
  const float* W_dt    = (const float*)d_in[5];
  const float* b_dt    = (const float*)d_in[6];
  const float* A_log   = (const float*)d_in[7];
  const float* D_skip  = (const float*)d_in[8];
  const float* W_out   = (const float*)d_in[9];
  const float* gamma   = (const float*)d_in[10];
  const float* beta    = (const float*)d_in[11];
  float* out = (float*)d_out;

  // workspace carve-up (256B aligned)
  char* ws = (char*)d_ws;
  size_t used = 0;
  auto alloc = [&](size_t bytes) -> char* {
    char* p = ws + used;
    used += (bytes + 255) & ~(size_t)255;
    return p;
  };
  u16* xz_bf     = (u16*)alloc((size_t)NTOK * 2 * D_INNER * 2);     // 33.5 MB
  float* pre     = (float*)alloc((size_t)NTOK * D_MODEL * 4);       // 16.8 MB; alias S
  char*  xw_reg  = alloc((size_t)NTOK * D_MODEL * 2 + (size_t)2 * D_INNER * D_MODEL * 2);
                                                                    // x_bf+Win_bf; alias hinit
  u16* u_bf      = (u16*)alloc((size_t)NTOK * D_INNER * 2);         // 16.8 MB
  u16* delta_bf  = (u16*)alloc((size_t)NTOK * D_INNER * 2);         // 16.8 MB
  u16* xdb_bf    = (u16*)alloc((size_t)NTOK * 128 * 2);             // 1 MB (96 padded to 128)
  u16* Wxp_bf    = (u16*)alloc((size_t)128 * D_INNER * 2);          // 0.5 MB
  u16* Wdt_bf    = (u16*)alloc((size_t)D_INNER * DT_RANK * 2);      // 0.26 MB
  u16* Wout_bf   = (u16*)alloc((size_t)D_MODEL * D_INNER * 2);      // 4.2 MB
  u16* yg_bf     = (u16*)alloc((size_t)NTOK * D_INNER * 2);         // 16.8 MB
  float* sumd    = (float*)alloc((size_t)NBATCH * NCHUNK * D_INNER * 4); // 1 MB
  float* xdb_part= (float*)alloc((size_t)KSPLIT * NTOK * 128 * 4);  // 16.8 MB

  // aliases (time-disjoint usage)
  u16* x_bf    = (u16*)xw_reg;                                    // dead after GEMM1
  u16* Win_bf  = (u16*)(xw_reg + (size_t)NTOK * D_MODEL * 2);     // dead after GEMM1
  float* S     = pre;                                             // pre written at stage 6
  float* hinit = (float*)xw_reg;                                  // 16.8 MB, after GEMM1

  if (ws_size < used) {   // signal: NaN output (insufficient workspace)
    hipMemsetAsync(d_out, 0xFF, (size_t)out_size * 4, stream);
    return;
  }

  const dim3 blk(256);

  // 0) all f32->bf16 conversions in one kernel (4 elems/thread)
  prep_k<<<(PTOT / 4 + 255) / 256, blk, 0, stream>>>(
      x, W_in, W_xproj, W_dt, W_out, x_bf, Win_bf, Wxp_bf, Wdt_bf, Wout_bf);

  // 1) in_proj: xz[4096,4096] = x[4096,1024] * W_in[4096,1024]^T  (bf16 out, BK=64)
  gemm_nt<128,128,64,4,4,1,0><<<dim3((2*D_INNER)/128, NTOK/128), blk, 0, stream>>>(
      x_bf, Win_bf, nullptr, xz_bf, nullptr, nullptr,
      0, D_MODEL, D_MODEL, D_MODEL, 2*D_INNER, 0);

  // 2) causal depthwise conv + silu -> u (bf16): 8 tokens x 4 channels per thread
  conv_silu_k<<<(NTOK / CONV_T) * (D_INNER / 4) / 256, blk, 0, stream>>>(
      xz_bf, W_conv, b_conv, u_bf);

  // 3) x_proj split-K=8: partials[8][4096][128] = u * W_xproj^T  (BK=32)
  gemm_nt<64,128,32,1,8,4,0><<<dim3(1, NTOK/64, KSPLIT), blk, 0, stream>>>(
      u_bf, Wxp_bf, xdb_part, nullptr, nullptr, nullptr,
      0, D_INNER / KSPLIT, D_INNER, D_INNER, 128, (size_t)NTOK * 128);
  reduce_conv_k<<<(NTOK * 128) / 256, blk, 0, stream>>>(xdb_part, xdb_bf);

  // 4) dt_proj + bias + softplus: delta[4096,2048] -> bf16  (BK=64: single K-iter)
  gemm_nt<128,128,64,4,4,2,0><<<dim3(D_INNER/128, NTOK/128), blk, 0, stream>>>(
      xdb_bf, Wdt_bf, nullptr, delta_bf, b_dt, nullptr,
      0, DT_RANK, 128, DT_RANK, D_INNER, 0);

  // 5) chunk-parallel selective scan + skip + gate -> yg (bf16)
  scan_p1<<<dim3(D_INNER/256, NCHUNK, NBATCH), blk, 0, stream>>>(
      delta_bf, u_bf, xdb_bf, A_log, S, sumd);
  scan_p2<<<dim3(D_INNER/16, NBATCH), blk, 0, stream>>>(
      S, sumd, A_log, hinit);
  scan_p3<<<dim3(D_INNER/256, NCHUNK, NBATCH), blk, 0, stream>>>(
      delta_bf, u_bf, xdb_bf, xz_bf, A_log, D_skip, hinit, yg_bf);

  // 6) out_proj + residual: pre = yg * W_out^T + x  (128x64, BK=64, XCD-panel swizzle)
  gemm_nt<128,64,64,4,2,3,1><<<dim3(NTOK/128, D_MODEL/64), blk, 0, stream>>>(
      yg_bf, Wout_bf, pre, nullptr, nullptr, x,
      0, D_INNER, D_INNER, D_INNER, D_MODEL, 0);

  // 7) LayerNorm
  ln_k<<<NTOK, blk, 0, stream>>>(pre, gamma, beta, out);
}

// Round 11
// 308.796 us; speedup vs baseline: 1.2615x; 1.0028x over previous
//
#include <hip/hip_runtime.h>
#include <cstdint>
#include <cstddef>

// ---------------- problem constants ----------------
#define D_MODEL   1024
#define D_STATE   16
#define D_CONV    4
#define D_INNER   2048
#define DT_RANK   64
#define NBATCH    2
#define SEQ       2048
#define NTOK      (NBATCH*SEQ)     // 4096 tokens
#define LN_EPSF   1e-5f
#define NCHUNK    64
#define TCHUNK    32               // SEQ / NCHUNK
#define KSPLIT    8                // x_proj split-K factor

typedef unsigned short u16;
typedef __bf16 bf16x8 __attribute__((ext_vector_type(8)));
typedef float  f32x4  __attribute__((ext_vector_type(4)));

__device__ __forceinline__ u16 f2bf(float f) {
  unsigned u = __float_as_uint(f);
  u += 0x7fffu + ((u >> 16) & 1u);          // round-to-nearest-even
  return (u16)(u >> 16);
}
__device__ __forceinline__ float bf2f(u16 v) {
  return __uint_as_float(((unsigned)v) << 16);
}
// unpack 8 bf16 (packed in uint4) -> 8 floats
__device__ __forceinline__ void unpack8(uint4 v, float* f) {
  f[0] = __uint_as_float(v.x << 16); f[1] = __uint_as_float(v.x & 0xffff0000u);
  f[2] = __uint_as_float(v.y << 16); f[3] = __uint_as_float(v.y & 0xffff0000u);
  f[4] = __uint_as_float(v.z << 16); f[5] = __uint_as_float(v.z & 0xffff0000u);
  f[6] = __uint_as_float(v.w << 16); f[7] = __uint_as_float(v.w & 0xffff0000u);
}

// async global->LDS, 16B per lane; lds dest must be wave-uniform base (+lane*16)
__device__ __forceinline__ void async16(const u16* g, u16* l) {
  __builtin_amdgcn_global_load_lds(
      (const __attribute__((address_space(1))) unsigned*)g,
      (__attribute__((address_space(3))) unsigned*)l, 16, 0, 0);
}

// ---------------- fused prep: all f32->bf16 conversions, 4 elems/thread ----------------
#define PN0 (NTOK*D_MODEL)          // x
#define PN1 (2*D_INNER*D_MODEL)     // W_in
#define PN2 (128*D_INNER)           // W_xproj (padded 96->128 rows)
#define PN3 (D_INNER*DT_RANK)       // W_dt
#define PN4 (D_MODEL*D_INNER)       // W_out
#define PTOT (PN0+PN1+PN2+PN3+PN4)
__global__ __launch_bounds__(256) void prep_k(
    const float* __restrict__ x, const float* __restrict__ W_in,
    const float* __restrict__ W_xproj, const float* __restrict__ W_dt,
    const float* __restrict__ W_out,
    u16* __restrict__ x_bf, u16* __restrict__ Win_bf, u16* __restrict__ Wxp_bf,
    u16* __restrict__ Wdt_bf, u16* __restrict__ Wout_bf)
{
  int i = (blockIdx.x * 256 + threadIdx.x) * 4;   // all segment sizes are 4-aligned
  const float* src; u16* dst; bool pad = false; int local = i;
  if (local < PN0)            { src = x;       dst = x_bf; }
  else if ((local -= PN0) < PN1) { src = W_in;    dst = Win_bf; }
  else if ((local -= PN1) < PN2) { src = W_xproj; dst = Wxp_bf; pad = (local >> 11) >= 96; }
  else if ((local -= PN2) < PN3) { src = W_dt;    dst = Wdt_bf; }
  else if ((local -= PN3) < PN4) { src = W_out;   dst = Wout_bf; }
  else return;
  ushort4 o;
  if (pad) { o = (ushort4){0,0,0,0}; }
  else {
    const float4 v = *(const float4*)(src + local);
    o = (ushort4){ f2bf(v.x), f2bf(v.y), f2bf(v.z), f2bf(v.w) };
  }
  *(ushort4*)(dst + local) = o;
}

// ---------------- bf16 NT GEMM: C[M,N] = A[M,K] * B[N,K]^T ----------------
// KB = K-tile (32 or 64). LDS rows are KB bf16; 16B-chunk column swizzled by
// cc ^= row&(CPR-1) so ds_read_b128 lands at worst 2-way (free) bank overlap.
// EPI: 0=f32 store, 1=bf16 store, 2=softplus(acc+bias[col])->bf16, 3=acc+res f32,
//      4=f32 store into partial plane blockIdx.z (split-K)
template<int BM, int BN, int KB, int WTM, int WTN, int EPI, int SWAPG>
__global__ __launch_bounds__(256) void gemm_nt(
    const u16* __restrict__ A, const u16* __restrict__ B,
    float* __restrict__ C, u16* __restrict__ Cb,
    const float* __restrict__ bias, const float* __restrict__ res,
    int kStart, int kEnd, int lda, int ldb, int ldc, size_t partStride)
{
  constexpr int CPR  = KB / 8;            // 16B chunks per LDS row
  constexpr int MASK = CPR - 1;
  constexpr int KSUB = KB / 32;           // 32-k MFMA sub-steps per tile
  constexpr int WAVES_N = BN / (16 * WTN);
  constexpr int ACH = BM * CPR;
  constexpr int BCH = BN * CPR;
  constexpr int ROUNDS = (ACH + BCH) / 256;

  __shared__ __align__(16) u16 lA[BM * KB];
  __shared__ __align__(16) u16 lB[BN * KB];

  const int tid  = threadIdx.x;
  const int w    = tid >> 6;
  const int lane = tid & 63;
  const int lrow = lane & 15;
  const int quad = lane >> 4;
  const int bm = (SWAPG ? blockIdx.x : blockIdx.y) * BM;
  const int bn = (SWAPG ? blockIdx.y : blockIdx.x) * BN;
  const int wave_m = (w / WAVES_N) * (16 * WTM);
  const int wave_n = (w % WAVES_N) * (16 * WTN);

  int kOff = 0;
  if constexpr (EPI == 4) kOff = blockIdx.z * (kEnd - kStart);

  f32x4 acc[WTM][WTN];
  #pragma unroll
  for (int mi = 0; mi < WTM; ++mi)
    #pragma unroll
    for (int ni = 0; ni < WTN; ++ni)
      acc[mi][ni] = (f32x4){0.f, 0.f, 0.f, 0.f};

  for (int k0 = kStart + kOff; k0 < kEnd + kOff; k0 += KB) {
    #pragma unroll
    for (int r = 0; r < ROUNDS; ++r) {
      const int c0 = r * 256 + w * 64;    // wave-uniform chunk base
      const int c  = c0 + lane;
      if (c0 < ACH) {
        const int row = c / CPR, cc = (c & MASK) ^ (row & MASK);
        async16(A + (size_t)(bm + row) * lda + k0 + cc * 8, &lA[c0 * 8]);
      } else {
        const int cb = c - ACH, c0b = c0 - ACH;
        const int row = cb / CPR, cc = (cb & MASK) ^ (row & MASK);
        async16(B + (size_t)(bn + row) * ldb + k0 + cc * 8, &lB[c0b * 8]);
      }
    }
    __syncthreads();   // drain global_load_lds + join

    #pragma unroll
    for (int s = 0; s < KSUB; ++s) {
      bf16x8 af[WTM], bfv[WTN];
      #pragma unroll
      for (int mi = 0; mi < WTM; ++mi) {
        const int R = wave_m + mi * 16 + lrow;
        af[mi] = *(const bf16x8*)&lA[R * KB + (((s * 4 + quad) ^ (R & MASK)) * 8)];
      }
      #pragma unroll
      for (int ni = 0; ni < WTN; ++ni) {
        const int R = wave_n + ni * 16 + lrow;
        bfv[ni] = *(const bf16x8*)&lB[R * KB + (((s * 4 + quad) ^ (R & MASK)) * 8)];
      }
      #pragma unroll
      for (int mi = 0; mi < WTM; ++mi)
        #pragma unroll
        for (int ni = 0; ni < WTN; ++ni)
          acc[mi][ni] = __builtin_amdgcn_mfma_f32_16x16x32_bf16(af[mi], bfv[ni], acc[mi][ni], 0, 0, 0);
    }
    __syncthreads();   // all waves done reading before next overwrite
  }

  #pragma unroll
  for (int mi = 0; mi < WTM; ++mi) {
    #pragma unroll
    for (int ni = 0; ni < WTN; ++ni) {
      const int col  = bn + wave_n + ni * 16 + lrow;
      const int row0 = bm + wave_m + mi * 16 + quad * 4;
      #pragma unroll
      for (int r = 0; r < 4; ++r) {
        float v = acc[mi][ni][r];
        const size_t idx = (size_t)(row0 + r) * ldc + col;
        if constexpr (EPI == 0) {
          C[idx] = v;
        } else if constexpr (EPI == 1) {
          Cb[idx] = f2bf(v);
        } else if constexpr (EPI == 2) {
          v += bias[col];
          v = (v > 20.f) ? v : log1pf(__expf(v));   // softplus
          Cb[idx] = f2bf(v);
        } else if constexpr (EPI == 3) {
          C[idx] = v + res[idx];
        } else {
          C[(size_t)blockIdx.z * partStride + idx] = v;
        }
      }
    }
  }
}

// ---------------- split-K reduce + bf16 convert (x_proj), 4 elems/thread ----------------
__global__ __launch_bounds__(256) void reduce_conv_k(
    const float* __restrict__ part, u16* __restrict__ dst)
{
  const int i = (blockIdx.x * 256 + threadIdx.x) * 4;   // over NTOK*128
  f32x4 s = (f32x4){0.f, 0.f, 0.f, 0.f};
  #pragma unroll
  for (int p = 0; p < KSPLIT; ++p) {
    const f32x4 v = *(const f32x4*)(part + (size_t)p * (NTOK * 128) + i);
    s[0] += v[0]; s[1] += v[1]; s[2] += v[2]; s[3] += v[3];
  }
  *(ushort4*)(dst + i) = (ushort4){ f2bf(s[0]), f2bf(s[1]), f2bf(s[2]), f2bf(s[3]) };
}

// ---------------- causal depthwise conv (D_CONV=4) + SiLU -> bf16 ----------------
// Sliding window: each thread handles 8 consecutive tokens x 4 channels.
#define CONV_T 8
__global__ __launch_bounds__(256) void conv_silu_k(
    const u16* __restrict__ xz, const float* __restrict__ Wc,
    const float* __restrict__ bc, u16* __restrict__ ub)
{
  const int tid = blockIdx.x * 256 + threadIdx.x;
  const int e   = (tid & 511) * 4;                  // channel group (consecutive lanes -> coalesced)
  const int tb  = tid >> 9;
  const int tok0 = tb * CONV_T;
  const int l0   = tok0 & (SEQ - 1);

  float4 wq[4];
  #pragma unroll
  for (int q = 0; q < 4; ++q) wq[q] = *(const float4*)(Wc + (e + q) * 4);
  const float4 bcv = *(const float4*)(bc + e);

  float p3[4], p2[4], p1[4];
  if (l0 == 0) {
    #pragma unroll
    for (int q = 0; q < 4; ++q) { p3[q] = 0.f; p2[q] = 0.f; p1[q] = 0.f; }
  } else {
    const ushort4 a = *(const ushort4*)(xz + (size_t)(tok0 - 3) * (2 * D_INNER) + e);
    const ushort4 b = *(const ushort4*)(xz + (size_t)(tok0 - 2) * (2 * D_INNER) + e);
    const ushort4 c = *(const ushort4*)(xz + (size_t)(tok0 - 1) * (2 * D_INNER) + e);
    p3[0]=bf2f(a.x); p3[1]=bf2f(a.y); p3[2]=bf2f(a.z); p3[3]=bf2f(a.w);
    p2[0]=bf2f(b.x); p2[1]=bf2f(b.y); p2[2]=bf2f(b.z); p2[3]=bf2f(b.w);
    p1[0]=bf2f(c.x); p1[1]=bf2f(c.y); p1[2]=bf2f(c.z); p1[3]=bf2f(c.w);
  }

  #pragma unroll
  for (int tt = 0; tt < CONV_T; ++tt) {
    const ushort4 xv = *(const ushort4*)(xz + (size_t)(tok0 + tt) * (2 * D_INNER) + e);
    float cur[4] = { bf2f(xv.x), bf2f(xv.y), bf2f(xv.z), bf2f(xv.w) };
    ushort4 o;
    u16* op = (u16*)&o;
    float a0 = ((const float*)&bcv)[0] + p3[0]*wq[0].x + p2[0]*wq[0].y + p1[0]*wq[0].z + cur[0]*wq[0].w;
    float a1 = ((const float*)&bcv)[1] + p3[1]*wq[1].x + p2[1]*wq[1].y + p1[1]*wq[1].z + cur[1]*wq[1].w;
    float a2 = ((const float*)&bcv)[2] + p3[2]*wq[2].x + p2[2]*wq[2].y + p1[2]*wq[2].z + cur[2]*wq[2].w;
    float a3 = ((const float*)&bcv)[3] + p3[3]*wq[3].x + p2[3]*wq[3].y + p1[3]*wq[3].z + cur[3]*wq[3].w;
    op[0] = f2bf(a0 / (1.f + __expf(-a0)));
    op[1] = f2bf(a1 / (1.f + __expf(-a1)));
    op[2] = f2bf(a2 / (1.f + __expf(-a2)));
    op[3] = f2bf(a3 / (1.f + __expf(-a3)));
    *(ushort4*)(ub + (size_t)(tok0 + tt) * D_INNER + e) = o;
    #pragma unroll
    for (int q = 0; q < 4; ++q) { p3[q] = p2[q]; p2[q] = p1[q]; p1[q] = cur[q]; }
  }
}

// ---------------- selective scan, chunk-parallel (3 passes, proven r8 path) ----------------
// A_log = log(1..16) => A[n] = -(n+1) exactly; exp(dlt*A[n]) = q^(n+1), q=exp(-dlt).
// Runtime-checked fast path; slow path preserves generality.
// S/hinit layout: [b][c][q][e][r], n = q*4+r, plane = D_INNER*4 floats.
#define SPLANE (D_INNER * 4)

// Pass 1: local scan with h=0 -> S, sum of delta -> sumd[b,c,e]
__global__ __launch_bounds__(256) void scan_p1(
    const u16* __restrict__ delta, const u16* __restrict__ ub,
    const u16* __restrict__ xdb, const float* __restrict__ A_log,
    float* __restrict__ S, float* __restrict__ sumd)
{
  const int e = blockIdx.x * 256 + threadIdx.x;
  const int c = blockIdx.y;
  const int b = blockIdx.z;
  float A[16], h[16];
  bool fast = true;
  #pragma unroll
  for (int n = 0; n < 16; ++n) {
    A[n] = -__expf(A_log[e * 16 + n]);
    fast = fast && (fabsf(A[n] + (float)(n + 1)) < 1e-3f);
    h[n] = 0.f;
  }
  float sd = 0.f;
  const int t0 = c * TCHUNK;
  #pragma unroll 2
  for (int t = 0; t < TCHUNK; ++t) {
    const size_t g = (size_t)(b * SEQ + t0 + t);
    const float dlt = bf2f(delta[g * D_INNER + e]);
    const float ut  = bf2f(ub[g * D_INNER + e]);
    float Bv[16];
    const u16* bp = xdb + g * 128 + DT_RANK;
    unpack8(*(const uint4*)bp, Bv);
    unpack8(*(const uint4*)(bp + 8), Bv + 8);
    sd += dlt;
    const float dbu = dlt * ut;
    float dA[16];
    if (fast) {
      const float q = __expf(-dlt);
      float p = 1.f;
      #pragma unroll
      for (int n = 0; n < 16; ++n) { p *= q; dA[n] = p; }
    } else {
      #pragma unroll
      for (int n = 0; n < 16; ++n) dA[n] = __expf(dlt * A[n]);
    }
    #pragma unroll
    for (int n = 0; n < 16; ++n)
      h[n] = dA[n] * h[n] + dbu * Bv[n];
  }
  const size_t sbase = ((size_t)(b * NCHUNK + c) * 4) * SPLANE + e * 4;
  #pragma unroll
  for (int q = 0; q < 4; ++q)
    *(f32x4*)&S[sbase + (size_t)q * SPLANE] = (f32x4){h[q*4], h[q*4+1], h[q*4+2], h[q*4+3]};
  sumd[(size_t)(b * NCHUNK + c) * D_INNER + e] = sd;
}

// Pass 2: sequential over chunks -> h_init (same layout as S)
// block: wave = q (n-group), lane: e_lo = lane>>2, r = lane&3 -> coalesced planes
__global__ __launch_bounds__(256) void scan_p2(
    const float* __restrict__ S, const float* __restrict__ sumd,
    const float* __restrict__ A_log, float* __restrict__ hinit)
{
  const int q    = threadIdx.x >> 6;
  const int lane = threadIdx.x & 63;
  const int e    = blockIdx.x * 16 + (lane >> 2);
  const int r    = lane & 3;
  const int b    = blockIdx.y;
  const int n    = q * 4 + r;
  const float An = -__expf(A_log[e * 16 + n]);
  float h = 0.f;
  size_t sidx = ((size_t)(b * NCHUNK) * 4 + q) * SPLANE + e * 4 + r;
  size_t didx = (size_t)(b * NCHUNK) * D_INNER + e;
  float s_cur  = S[sidx];
  float sd_cur = sumd[didx];
  for (int c = 0; c < NCHUNK; ++c) {
    hinit[sidx] = h;
    float s_nxt = 0.f, sd_nxt = 0.f;
    if (c + 1 < NCHUNK) {
      s_nxt  = S[sidx + 4 * SPLANE];
      sd_nxt = sumd[didx + D_INNER];
    }
    h = __expf(An * sd_cur) * h + s_cur;
    s_cur = s_nxt; sd_cur = sd_nxt;
    sidx += 4 * SPLANE;
    didx += D_INNER;
  }
}

// Pass 3: rescan from h_init, fused y-dot + skip + gate -> yg (bf16)
__global__ __launch_bounds__(256) void scan_p3(
    const u16* __restrict__ delta, const u16* __restrict__ ub,
    const u16* __restrict__ xdb, const u16* __restrict__ xz,
    const float* __restrict__ A_log, const float* __restrict__ D_skip,
    const float* __restrict__ hinit, u16* __restrict__ yg)
{
  const int e = blockIdx.x * 256 + threadIdx.x;
  const int c = blockIdx.y;
  const int b = blockIdx.z;
  float A[16], h[16];
  bool fast = true;
  #pragma unroll
  for (int n = 0; n < 16; ++n) {
    A[n] = -__expf(A_log[e * 16 + n]);
    fast = fast && (fabsf(A[n] + (float)(n + 1)) < 1e-3f);
  }
  const size_t sbase = ((size_t)(b * NCHUNK + c) * 4) * SPLANE + e * 4;
  #pragma unroll
  for (int q = 0; q < 4; ++q) {
    f32x4 v = *(const f32x4*)&hinit[sbase + (size_t)q * SPLANE];
    h[q*4] = v[0]; h[q*4+1] = v[1]; h[q*4+2] = v[2]; h[q*4+3] = v[3];
  }
  const float De = D_skip[e];
  const int t0 = c * TCHUNK;
  #pragma unroll 2
  for (int t = 0; t < TCHUNK; ++t) {
    const size_t g = (size_t)(b * SEQ + t0 + t);
    const float dlt = bf2f(delta[g * D_INNER + e]);
    const float ut  = bf2f(ub[g * D_INNER + e]);
    const float z   = bf2f(xz[g * (2 * D_INNER) + D_INNER + e]);
    float Bv[16], Cv[16];
    const u16* bp = xdb + g * 128 + DT_RANK;
    unpack8(*(const uint4*)bp, Bv);
    unpack8(*(const uint4*)(bp + 8), Bv + 8);
    unpack8(*(const uint4*)(bp + 16), Cv);
    unpack8(*(const uint4*)(bp + 24), Cv + 8);
    const float dbu = dlt * ut;
    float dA[16];
    if (fast) {
      const float q = __expf(-dlt);
      float p = 1.f;
      #pragma unroll
      for (int n = 0; n < 16; ++n) { p *= q; dA[n] = p; }
    } else {
      #pragma unroll
      for (int n = 0; n < 16; ++n) dA[n] = __expf(dlt * A[n]);
    }
    float y = 0.f;
    #pragma unroll
    for (int n = 0; n < 16; ++n) {
      h[n] = dA[n] * h[n] + dbu * Bv[n];
      y += h[n] * Cv[n];
    }
    y += ut * De;
    const float gt = z / (1.f + __expf(-z));
    yg[g * D_INNER + e] = f2bf(y * gt);
  }
}

// ---------------- LayerNorm, one block per token (f32 pre, float4 loads) ----------------
__global__ __launch_bounds__(256) void ln_k(const float* __restrict__ pre,
                                            const float* __restrict__ gamma,
                                            const float* __restrict__ beta,
                                            float* __restrict__ out)
{
  const int tok = blockIdx.x;
  const int t   = threadIdx.x;
  const float4 pv = *(const float4*)(pre + (size_t)tok * D_MODEL + t * 4);
  float v[4] = { pv.x, pv.y, pv.z, pv.w };
  float s = v[0] + v[1] + v[2] + v[3];
  float s2 = v[0]*v[0] + v[1]*v[1] + v[2]*v[2] + v[3]*v[3];
  #pragma unroll
  for (int off = 32; off >= 1; off >>= 1) {
    s  += __shfl_xor(s,  off);
    s2 += __shfl_xor(s2, off);
  }
  __shared__ float red[8];
  if ((t & 63) == 0) { red[t >> 6] = s; red[4 + (t >> 6)] = s2; }
  __syncthreads();
  if (t == 0) {
    const float ts  = red[0] + red[1] + red[2] + red[3];
    const float ts2 = red[4] + red[5] + red[6] + red[7];
    const float mu  = ts * (1.f / D_MODEL);
    const float var = ts2 * (1.f / D_MODEL) - mu * mu;
    red[0] = mu; red[1] = rsqrtf(var + LN_EPSF);
  }
  __syncthreads();
  const float mu = red[0], rv = red[1];
  const float4 gv = *(const float4*)(gamma + t * 4);
  const float4 bv = *(const float4*)(beta + t * 4);
  f32x4 o;
  o[0] = (v[0] - mu) * rv * gv.x + bv.x;
  o[1] = (v[1] - mu) * rv * gv.y + bv.y;
  o[2] = (v[2] - mu) * rv * gv.z + bv.z;
  o[3] = (v[3] - mu) * rv * gv.w + bv.w;
  *(f32x4*)(out + (size_t)tok * D_MODEL + t * 4) = o;
}

// ---------------- host launch ----------------
extern "C" void kernel_launch(void* const* d_in, const int* in_sizes, int n_in,
                              void* d_out, int out_size, void* d_ws, size_t ws_size,
                              hipStream_t stream) {
  const float* x       = (const float*)d_in[0];
  const float* W_in    = (const float*)d_in[1];
  const float* W_conv  = (const float*)d_in[2];
  const float* b_conv  = (const float*)d_in[3];
  const float* W_xproj = (const float*)d_in[4];
  const float* W_dt    = (const float*)d_in[5];
  const float* b_dt    = (const float*)d_in[6];
  const float* A_log   = (const float*)d_in[7];
  const float* D_skip  = (const float*)d_in[8];
  const float* W_out   = (const float*)d_in[9];
  const float* gamma   = (const float*)d_in[10];
  const float* beta    = (const float*)d_in[11];
  float* out = (float*)d_out;

  // workspace carve-up (256B aligned)
  char* ws = (char*)d_ws;
  size_t used = 0;
  auto alloc = [&](size_t bytes) -> char* {
    char* p = ws + used;
    used += (bytes + 255) & ~(size_t)255;
    return p;
  };
  u16* xz_bf     = (u16*)alloc((size_t)NTOK * 2 * D_INNER * 2);     // 33.5 MB
  float* pre     = (float*)alloc((size_t)NTOK * D_MODEL * 4);       // 16.8 MB (f32)
  char*  xw_reg  = alloc((size_t)NTOK * D_MODEL * 2 + (size_t)2 * D_INNER * D_MODEL * 2);
                                                                    // x_bf+Win_bf 16.8; alias hinit
  u16* u_bf      = (u16*)alloc((size_t)NTOK * D_INNER * 2);         // 16.8 MB
  u16* delta_bf  = (u16*)alloc((size_t)NTOK * D_INNER * 2);         // 16.8 MB
  u16* xdb_bf    = (u16*)alloc((size_t)NTOK * 128 * 2);             // 1 MB (96 padded to 128)
  u16* Wxp_bf    = (u16*)alloc((size_t)128 * D_INNER * 2);          // 0.5 MB
  u16* Wdt_bf    = (u16*)alloc((size_t)D_INNER * DT_RANK * 2);      // 0.26 MB
  u16* Wout_bf   = (u16*)alloc((size_t)D_MODEL * D_INNER * 2);      // 4.2 MB
  u16* yg_bf     = (u16*)alloc((size_t)NTOK * D_INNER * 2);         // 16.8 MB
  float* sumd    = (float*)alloc((size_t)NBATCH * NCHUNK * D_INNER * 4); // 1 MB
  float* xdb_part= (float*)alloc((size_t)KSPLIT * NTOK * 128 * 4);  // 16.8 MB; alias S

  // aliases (time-disjoint usage)
  u16* x_bf    = (u16*)xw_reg;                                    // dead after GEMM1
  u16* Win_bf  = (u16*)(xw_reg + (size_t)NTOK * D_MODEL * 2);     // dead after GEMM1
  float* S     = xdb_part;                                        // xdb_part dead after reduce
  float* hinit = (float*)xw_reg;                                  // 16.8 MB, after GEMM1

  if (ws_size < used) {   // signal: NaN output (insufficient workspace)
    hipMemsetAsync(d_out, 0xFF, (size_t)out_size * 4, stream);
    return;
  }

  const dim3 blk(256);

  // 0) all f32->bf16 conversions in one kernel (4 elems/thread)
  prep_k<<<(PTOT / 4 + 255) / 256, blk, 0, stream>>>(
      x, W_in, W_xproj, W_dt, W_out, x_bf, Win_bf, Wxp_bf, Wdt_bf, Wout_bf);

  // 1) in_proj: xz[4096,4096] = x[4096,1024] * W_in[4096,1024]^T  (bf16 out, BK=64)
  gemm_nt<128,128,64,4,4,1,0><<<dim3((2*D_INNER)/128, NTOK/128), blk, 0, stream>>>(
      x_bf, Win_bf, nullptr, xz_bf, nullptr, nullptr,
      0, D_MODEL, D_MODEL, D_MODEL, 2*D_INNER, 0);

  // 2) causal depthwise conv + silu -> u (bf16): 8 tokens x 4 channels per thread
  conv_silu_k<<<(NTOK / CONV_T) * (D_INNER / 4) / 256, blk, 0, stream>>>(
      xz_bf, W_conv, b_conv, u_bf);

  // 3) x_proj split-K=8: partials[8][4096][128] = u * W_xproj^T  (BK=32)
  gemm_nt<64,128,32,1,8,4,0><<<dim3(1, NTOK/64, KSPLIT), blk, 0, stream>>>(
      u_bf, Wxp_bf, xdb_part, nullptr, nullptr, nullptr,
      0, D_INNER / KSPLIT, D_INNER, D_INNER, 128, (size_t)NTOK * 128);
  reduce_conv_k<<<(NTOK * 128) / 1024, blk, 0, stream>>>(xdb_part, xdb_bf);

  // 4) dt_proj + bias + softplus: delta[4096,2048] -> bf16  (BK=64: single K-iter)
  gemm_nt<128,128,64,4,4,2,0><<<dim3(D_INNER/128, NTOK/128), blk, 0, stream>>>(
      xdb_bf, Wdt_bf, nullptr, delta_bf, b_dt, nullptr,
      0, DT_RANK, 128, DT_RANK, D_INNER, 0);

  // 5) chunk-parallel selective scan + skip + gate -> yg (bf16)  [3-kernel proven path]
  scan_p1<<<dim3(D_INNER/256, NCHUNK, NBATCH), blk, 0, stream>>>(
      delta_bf, u_bf, xdb_bf, A_log, S, sumd);
  scan_p2<<<dim3(D_INNER/16, NBATCH), blk, 0, stream>>>(
      S, sumd, A_log, hinit);
  scan_p3<<<dim3(D_INNER/256, NCHUNK, NBATCH), blk, 0, stream>>>(
      delta_bf, u_bf, xdb_bf, xz_bf, A_log, D_skip, hinit, yg_bf);

  // 6) out_proj + residual: pre[4096,1024] = yg * W_out^T + x  (f32, 128x64, BK=64)
  gemm_nt<128,64,64,4,2,3,1><<<dim3(NTOK/128, D_MODEL/64), blk, 0, stream>>>(
      yg_bf, Wout_bf, pre, nullptr, nullptr, x,
      0, D_INNER, D_INNER, D_INNER, D_MODEL, 0);

  // 7) LayerNorm (f32 pre, vectorized)
  ln_k<<<NTOK, blk, 0, stream>>>(pre, gamma, beta, out);
}